// Round 8
// baseline (835.733 us; speedup 1.0000x reference)
//
#include <hip/hip_runtime.h>
#include <cstddef>
#include <cstdint>

typedef _Float16 h4 __attribute__((ext_vector_type(4)));
typedef _Float16 h8 __attribute__((ext_vector_type(8)));
typedef float    f4 __attribute__((ext_vector_type(4)));
typedef int      i4 __attribute__((ext_vector_type(4)));

#define NN      50000
#define IND     512
#define HIDN    256
#define E2P     400000
#define EDD     800000
#define NBLK    196    // scan blocks
#define SCN     50176  // NBLK*256: scan domain (>= NN and >= key space)
#define EBLK    1563   // ceil(E2P/256)
#define NBPN    1563   // ceil(NN/32): k_bpN blocks (32 nodes each)
#define BCAP    1024   // LDS slot cache per block (P(overflow) ~ 0; guarded fallback)

// ---- workspace layout (bytes) ----
// logfA/logfB (2 x 12.8MB) alias hf (dead after k_edge)
#define OFF_HF16    ((size_t)0)            // 25,600,000  f16 h [NN][256]
#define OFF_LOGFA   ((size_t)0)            // 12,800,000  f16 [EDD][8] OUTGOING layout
#define OFF_LOGFB   ((size_t)12800000)     // 12,800,000  ping-pong partner
#define OFF_Z       ((size_t)25600000)     //  3,200,000  f32 [NN][16]: [0:8]=log_phi
#define OFF_DEG     ((size_t)28800000)     //    204,800  int [SCN]
#define OFF_LOGDEG  ((size_t)29004800)     //    200,000  f32
#define OFF_DEGC    ((size_t)29204800)     //    200,000  f32
#define OFF_BASE    ((size_t)29404800)     //    204,800  int [SCN] (dst-CSR scan)
#define OFF_CNT     ((size_t)29609600)     //    204,800  int [SCN] (scan scratch / counters)
#define OFF_BLK     ((size_t)29814400)     //      4,096  int (scan block sums)
#define OFF_WT      ((size_t)29818496)     //    262,144  f16 enc_w1^T
#define OFF_BT      ((size_t)30080640)     //     69,632  f16 edge_w1 perm^T (h8-gather K-order)
#define OFF_RS      ((size_t)30150272)     //        512  f32 Rs[64] + alpha at [64]
#define OFF_WSYM    ((size_t)30150784)     //  1,600,000  f32 [E2P] wsym2 (SORTED pair order)
#define OFF_POS     ((size_t)31750784)     //  3,200,000  int [EDD] CSR slot of each directed edge
#define OFF_ORDER   ((size_t)34950784)     //  1,600,000  int [E2P] pairs sorted by locality key
#define OFF_BASE2   ((size_t)36550784)     //    204,800  int [SCN] (pair-key CSR)
#define OFF_OFS2    ((size_t)36755584)     //    204,800  int [SCN] (counters)
#define OFF_EIS     ((size_t)36960384)     //  3,200,000  int2 [E2P] {src,dst} sorted
#define OFF_M       ((size_t)40160384)     // 12,800,000  f16 [EDD][8] outgoing-m, slot-indexed
#define OFF_WNS     ((size_t)52960384)     //  6,400,000  float2 [EDD] {w,nrm} per slot
#define OFF_PPOS    ((size_t)59360384)     //  3,200,000  int [EDD] partner slot
#define WS_NEED     ((size_t)62560384)

// 2-D locality key: src-bucket (1024 nodes) major, dst-bucket (64 nodes) minor
__device__ __forceinline__ int key2(int s, int d) {
    return ((s >> 10) << 10) | (d >> 6);
}

// bijective XCD-aware block remap: each XCD gets a contiguous chunk
__device__ __forceinline__ int xcd_swz(int bid, int nwg) {
    int q = nwg >> 3, r = nwg & 7;
    int x = bid & 7, idx = bid >> 3;
    return (x < r ? x * (q + 1) : r * (q + 1) + (x - r) * q) + idx;
}

// ---------------- degree count + pair-key count (fused) ----------------
__global__ void k_deg(const int* __restrict__ ei, int* __restrict__ deg,
                      int* __restrict__ cnt2) {
    int e = blockIdx.x * 256 + threadIdx.x;   // grid exact: EDD
    int v = ei[e];
    atomicAdd(&deg[v], 1);
    if (e < E2P) {
        int d = ei[EDD + e];
        atomicAdd(&cnt2[key2(v, d)], 1);
    }
}

__global__ void k_node(const int* __restrict__ deg, float* __restrict__ logdeg,
                       float* __restrict__ degc) {
    int n = blockIdx.x * 256 + threadIdx.x;
    if (n < NN) {
        float d = (float)deg[n];
        logdeg[n] = logf(d + 1.0f);
        degc[n]   = fmaxf(d, 1.0f);
    }
}

// ---------------- SCN-sized prefix-sum (3 tiny kernels, grid = NBLK exact) ------------
__global__ void k_scan1(const int* __restrict__ deg, int* __restrict__ incl,
                        int* __restrict__ blk) {
    __shared__ int sm[256];
    int i = blockIdx.x * 256 + threadIdx.x;
    int v = deg[i];
    sm[threadIdx.x] = v;
    __syncthreads();
    for (int off = 1; off < 256; off <<= 1) {
        int t = (threadIdx.x >= off) ? sm[threadIdx.x - off] : 0;
        __syncthreads();
        sm[threadIdx.x] += t;
        __syncthreads();
    }
    incl[i] = sm[threadIdx.x];
    if (threadIdx.x == 255) blk[blockIdx.x] = sm[255];
}

__global__ void k_scan2(int* __restrict__ blk) {
    __shared__ int sm[256];
    int v = (threadIdx.x < NBLK) ? blk[threadIdx.x] : 0;
    sm[threadIdx.x] = v;
    __syncthreads();
    for (int off = 1; off < 256; off <<= 1) {
        int t = (threadIdx.x >= off) ? sm[threadIdx.x - off] : 0;
        __syncthreads();
        sm[threadIdx.x] += t;
        __syncthreads();
    }
    if (threadIdx.x < NBLK) blk[threadIdx.x] = sm[threadIdx.x];
}

__global__ void k_scan3(const int* __restrict__ incl, const int* __restrict__ deg,
                        const int* __restrict__ blk, int* __restrict__ base) {
    int i = blockIdx.x * 256 + threadIdx.x;
    int off = (blockIdx.x > 0) ? blk[blockIdx.x - 1] : 0;
    base[i] = off + incl[i] - deg[i];
}

// pos[e] = CSR slot of directed edge e within its dst node's segment
__global__ void k_pos(const int* __restrict__ ei, const int* __restrict__ base,
                      int* __restrict__ cnt, int* __restrict__ pos) {
    int e = blockIdx.x * 256 + threadIdx.x;   // grid exact: EDD
    int dstn = ei[EDD + e];
    pos[e] = base[dstn] + atomicAdd(&cnt[dstn], 1);
}

__global__ void k_order(const int* __restrict__ ei, const int* __restrict__ base2,
                        int* __restrict__ ofs2, int* __restrict__ order) {
    int p = blockIdx.x * 256 + threadIdx.x;
    if (p < E2P) {
        int k = key2(ei[p], ei[EDD + p]);
        order[base2[k] + atomicAdd(&ofs2[k], 1)] = p;
    }
}

// eiS[i] = {src,dst} of pair order[i]
__global__ void k_gath(const int* __restrict__ ei, const int* __restrict__ order,
                       int2* __restrict__ eiS) {
    int i = blockIdx.x * 256 + threadIdx.x;
    if (i < E2P) {
        int p = order[i];
        eiS[i] = make_int2(ei[p], ei[EDD + p]);
    }
}

// ---------------- weight prep ----------------
// Bt K-order for h8 gathers: MFMA step tm (0..15), lane q, element e=2j+typ
//   k' = tm*32 + q*8 + 2j + typ  <->  column c = (tm>>1)*32 + q*8 + (tm&1)*4 + j
//   typ 0 = product feature (row c), typ 1 = absdiff (row 256+c). k'=512,513: struct.
__global__ void k_prep(const float* __restrict__ enc_w1, const float* __restrict__ edge_w1,
                       const float* __restrict__ R_raw, const float* __restrict__ Rsl,
                       const float* __restrict__ mlog,
                       _Float16* __restrict__ Wt, _Float16* __restrict__ Bt,
                       float* __restrict__ Rs) {
    int gid = blockIdx.x * 256 + threadIdx.x;
    if (gid < 256 * 512) {                       // Wt[n][k] = enc_w1[k][n]
        int n = gid >> 9, k = gid & 511;
        Wt[n * 512 + k] = (_Float16)enc_w1[k * 256 + n];
        return;
    }
    int g2 = gid - 256 * 512;
    if (g2 < 64 * 544) {                         // Bt[n][k'] with h8-gather K perm
        int n = g2 / 544, k = g2 - n * 544;
        float v = 0.0f;
        if (k < 512) {
            int tm = k >> 5, r = k & 31;
            int qq = r >> 3, jj = (r >> 1) & 3, typ = k & 1;
            int c = (tm >> 1) * 32 + qq * 8 + (tm & 1) * 4 + jj;
            v = edge_w1[(typ ? 256 + c : c) * 64 + n];
        } else if (k < 514) {
            v = edge_w1[k * 64 + n];
        }
        Bt[n * 544 + k] = (_Float16)v;
        return;
    }
    int g3 = g2 - 64 * 544;
    if (g3 < 64) {
        int c = g3 >> 3, d = g3 & 7;
        float rv = 0.5f * (R_raw[c * 8 + d] + R_raw[d * 8 + c]);
        float s  = log1pf(expf(Rsl[0])) + 1e-6f;
        Rs[g3] = s * tanhf(rv);
        return;
    }
    if (g3 == 64) {
        Rs[64] = 1.5f / (1.0f + expf(-mlog[0]));
    }
}

// ---------------- encoder layer 1: bulk x-register preload (deep MLP) -----------------
// 64 rows/block, W via double-buffered LDS; x: all 16 k-slices preloaded -> 32 loads
// in flight per wave (counted-vmcnt pipeline), then converted to f16 once.
__global__ __launch_bounds__(256, 1) void k_enc(const float* __restrict__ x,
                                                const _Float16* __restrict__ Wt,
                                                const float* __restrict__ b1,
                                                _Float16* __restrict__ hf) {
    __shared__ _Float16 WL[2][256 * 40];   // 2 x 20 KB
    const int tid = threadIdx.x;
    const int wid = tid >> 6;
    const int lane = tid & 63;
    const int l15 = lane & 15;
    const int q = lane >> 4;
    const int m0 = blockIdx.x * 64;
    const int row = m0 + wid * 16 + l15;
    const bool ract = (row < NN);
    const float* xrow = x + (size_t)row * IND;

    // bulk preload of x (all 16 k-slices)
    f4 xk0[16], xk1[16];
#pragma unroll
    for (int kt = 0; kt < 16; kt++) {
        if (ract) {
            const f4* xp = (const f4*)(xrow + kt * 32 + q * 8);
            xk0[kt] = xp[0]; xk1[kt] = xp[1];
        } else {
            xk0[kt] = (f4){0, 0, 0, 0}; xk1[kt] = (f4){0, 0, 0, 0};
        }
    }
    h8 xh[16];
#pragma unroll
    for (int kt = 0; kt < 16; kt++) {
#pragma unroll
        for (int u = 0; u < 4; u++) {
            xh[kt][u]     = (_Float16)xk0[kt][u];
            xh[kt][4 + u] = (_Float16)xk1[kt][u];
        }
    }

    f4 acc[16];
#pragma unroll
    for (int i = 0; i < 16; i++) acc[i] = (f4){0.f, 0.f, 0.f, 0.f};

    const int wn = tid >> 2;          // staging: W row
    const int wo = (tid & 3) * 8;     // staging: col offset

    h8 wreg[4];
#pragma unroll
    for (int rep = 0; rep < 4; rep++)
        wreg[rep] = *(const h8*)(Wt + (size_t)(rep * 64 + wn) * IND + wo);

#pragma unroll
    for (int kt = 0; kt < 16; kt++) {
        const int cur = kt & 1;
#pragma unroll
        for (int rep = 0; rep < 4; rep++)
            *(h8*)&WL[cur][(rep * 64 + wn) * 40 + wo] = wreg[rep];
        __syncthreads();
        if (kt < 15) {                  // prefetch next W slice while MFMAs run
            const int kc = (kt + 1) * 32;
#pragma unroll
            for (int rep = 0; rep < 4; rep++)
                wreg[rep] = *(const h8*)(Wt + (size_t)(rep * 64 + wn) * IND + kc + wo);
        }
#pragma unroll
        for (int nt = 0; nt < 16; nt++) {
            h8 b = *(const h8*)&WL[cur][(nt * 16 + l15) * 40 + q * 8];
            acc[nt] = __builtin_amdgcn_mfma_f32_16x16x32_f16(xh[kt], b, acc[nt], 0, 0, 0);
        }
        __syncthreads();   // protect WL[cur] until all waves' MFMA reads done
    }
#pragma unroll
    for (int nt = 0; nt < 16; nt++) {
        int col = nt * 16 + l15;
        float bv = b1[col];
#pragma unroll
        for (int reg = 0; reg < 4; reg++) {
            int orow = m0 + wid * 16 + q * 4 + reg;
            if (orow < NN) {
                float v = acc[nt][reg] + bv;
                hf[(size_t)orow * HIDN + col] = (_Float16)fmaxf(v, 0.f);
            }
        }
    }
}

// ---------------- encoder layer 2 + log_softmax -> Z[n][0:8] ----------------
__global__ void k_logits(const _Float16* __restrict__ hf, const float* __restrict__ w2,
                         const float* __restrict__ b2, float* __restrict__ Z) {
    __shared__ float w2L[2048];
    for (int i = threadIdx.x; i < 2048; i += 256) w2L[i] = w2[i];
    __syncthreads();
    int n = blockIdx.x * 256 + threadIdx.x;
    if (n >= NN) return;
    float sum[8];
#pragma unroll
    for (int c = 0; c < 8; c++) sum[c] = b2[c];
    for (int kb = 0; kb < 32; kb++) {
        h8 hv = *(const h8*)(hf + (size_t)n * HIDN + kb * 8);
#pragma unroll
        for (int u = 0; u < 8; u++) {
            float hx = (float)hv[u];
            const float* wr = &w2L[(kb * 8 + u) * 8];
#pragma unroll
            for (int c = 0; c < 8; c++) sum[c] += hx * wr[c];
        }
    }
    float mx = sum[0];
#pragma unroll
    for (int c = 1; c < 8; c++) mx = fmaxf(mx, sum[c]);
    float se = 0.f;
#pragma unroll
    for (int c = 0; c < 8; c++) se += __expf(sum[c] - mx);
    float lse = __logf(se);
#pragma unroll
    for (int c = 0; c < 8; c++) Z[(size_t)n * 16 + c] = sum[c] - mx - lse;
}

// ---------------- edge MLP over locality-sorted pairs + XCD chunking -----------------
__global__ __launch_bounds__(256) void k_edge(const int2* __restrict__ eiS,
        const _Float16* __restrict__ hf, const float* __restrict__ logdeg,
        const _Float16* __restrict__ BtG, const float* __restrict__ eb1,
        const float* __restrict__ ew2, const float* __restrict__ eb2,
        float* __restrict__ wsym2) {
    __shared__ _Float16 BtL[64 * 136];
    const int tid = threadIdx.x;
    const int wid = tid >> 6;
    const int lane = tid & 63;
    const int l15 = lane & 15;
    const int q = lane >> 4;
    const int eb = xcd_swz(blockIdx.x, gridDim.x) * 128;  // grid exact: E2P/128 = 3125

    int sidx[2], didx[2];
    float la[2], lb[2];
#pragma unroll
    for (int mt = 0; mt < 2; mt++) {
        int e = eb + wid * 32 + mt * 16 + l15;   // always < E2P
        int2 sd = eiS[e];
        sidx[mt] = sd.x;
        didx[mt] = sd.y;
        la[mt] = logdeg[sidx[mt]];
        lb[mt] = logdeg[didx[mt]];
    }

    f4 acc[2][4];
#pragma unroll
    for (int a = 0; a < 2; a++)
#pragma unroll
        for (int b = 0; b < 4; b++) acc[a][b] = (f4){0.f, 0.f, 0.f, 0.f};

    const _Float16* hq = hf + q * 8;            // lane's 16B column slice
    h8 curS[2], curD[2];
#pragma unroll
    for (int mt = 0; mt < 2; mt++) {            // kk=0 fragments (cols q*8..q*8+7)
        curS[mt] = *(const h8*)(hq + (size_t)sidx[mt] * HIDN);
        curD[mt] = *(const h8*)(hq + (size_t)didx[mt] * HIDN);
    }

    for (int ph = 0; ph < 4; ph++) {
        __syncthreads();
        {   // stage 64 rows x 128 cols of Bt (r=tid>>2 mapping: conflict-free writes)
            const int r = tid >> 2;
            const int c0 = tid & 3;
            const int kbase = ph * 128;
#pragma unroll
            for (int i2 = 0; i2 < 4; i2++) {
                int ck = c0 + i2 * 4;
                *(h8*)&BtL[r * 136 + ck * 8] =
                    *(const h8*)(BtG + (size_t)r * 544 + kbase + ck * 8);
            }
        }
        __syncthreads();
#pragma unroll
        for (int kk2 = 0; kk2 < 2; kk2++) {
            const int kk = ph * 2 + kk2;
            h8 nxtS[2], nxtD[2];
            if (kk < 7) {                        // prefetch next 16B slice
                const int c1 = (kk + 1) * 32;
#pragma unroll
                for (int mt = 0; mt < 2; mt++) {
                    nxtS[mt] = *(const h8*)(hq + (size_t)sidx[mt] * HIDN + c1);
                    nxtD[mt] = *(const h8*)(hq + (size_t)didx[mt] * HIDN + c1);
                }
            }
            const int ko = kk2 * 64 + q * 8;
            // half 0 (cols +0..3)
            {
                h8 a0[2];
#pragma unroll
                for (int mt = 0; mt < 2; mt++) {
#pragma unroll
                    for (int j = 0; j < 4; j++) {
                        float x1 = (float)curS[mt][j], x2 = (float)curD[mt][j];
                        a0[mt][2 * j]     = (_Float16)(x1 * x2);
                        a0[mt][2 * j + 1] = (_Float16)fabsf(x1 - x2);
                    }
                }
                h8 bf[4];
#pragma unroll
                for (int nt = 0; nt < 4; nt++)
                    bf[nt] = *(const h8*)&BtL[(nt * 16 + l15) * 136 + ko];
#pragma unroll
                for (int mt = 0; mt < 2; mt++)
#pragma unroll
                    for (int nt = 0; nt < 4; nt++)
                        acc[mt][nt] = __builtin_amdgcn_mfma_f32_16x16x32_f16(a0[mt], bf[nt], acc[mt][nt], 0, 0, 0);
            }
            // half 1 (cols +4..7)
            {
                h8 a1[2];
#pragma unroll
                for (int mt = 0; mt < 2; mt++) {
#pragma unroll
                    for (int j = 0; j < 4; j++) {
                        float x1 = (float)curS[mt][4 + j], x2 = (float)curD[mt][4 + j];
                        a1[mt][2 * j]     = (_Float16)(x1 * x2);
                        a1[mt][2 * j + 1] = (_Float16)fabsf(x1 - x2);
                    }
                }
                h8 bf[4];
#pragma unroll
                for (int nt = 0; nt < 4; nt++)
                    bf[nt] = *(const h8*)&BtL[(nt * 16 + l15) * 136 + ko + 32];
#pragma unroll
                for (int mt = 0; mt < 2; mt++)
#pragma unroll
                    for (int nt = 0; nt < 4; nt++)
                        acc[mt][nt] = __builtin_amdgcn_mfma_f32_16x16x32_f16(a1[mt], bf[nt], acc[mt][nt], 0, 0, 0);
            }
            if (kk < 7) {
#pragma unroll
                for (int mt = 0; mt < 2; mt++) { curS[mt] = nxtS[mt]; curD[mt] = nxtD[mt]; }
            }
        }
    }

    // struct features step (k' = 512..543, only 512/513 nonzero)
    __syncthreads();
    {
        const int r = tid >> 2, ck = tid & 3;
        *(h8*)&BtL[r * 136 + ck * 8] = *(const h8*)(BtG + (size_t)r * 544 + 512 + ck * 8);
    }
    __syncthreads();
    {
        h8 bf[4];
#pragma unroll
        for (int nt = 0; nt < 4; nt++)
            bf[nt] = *(const h8*)&BtL[(nt * 16 + l15) * 136 + q * 8];
#pragma unroll
        for (int mt = 0; mt < 2; mt++) {
            h8 a = (h8){0, 0, 0, 0, 0, 0, 0, 0};
            if (q == 0) {
                a[0] = (_Float16)(la[mt] + lb[mt]);
                a[1] = (_Float16)fabsf(la[mt] - lb[mt]);
            }
#pragma unroll
            for (int nt = 0; nt < 4; nt++)
                acc[mt][nt] = __builtin_amdgcn_mfma_f32_16x16x32_f16(a, bf[nt], acc[mt][nt], 0, 0, 0);
        }
    }

    float b1v[4], w2v[4];
#pragma unroll
    for (int nt = 0; nt < 4; nt++) {
        int col = nt * 16 + l15;
        b1v[nt] = eb1[col];
        w2v[nt] = ew2[col];
    }
    const float b2s = eb2[0];
    float part[2][4];
#pragma unroll
    for (int mt = 0; mt < 2; mt++)
#pragma unroll
        for (int reg = 0; reg < 4; reg++) {
            float s = 0.f;
#pragma unroll
            for (int nt = 0; nt < 4; nt++) {
                float v = acc[mt][nt][reg] + b1v[nt];
                s += fmaxf(v, 0.f) * w2v[nt];
            }
            part[mt][reg] = s;
        }
#pragma unroll
    for (int off = 1; off < 16; off <<= 1)
#pragma unroll
        for (int mt = 0; mt < 2; mt++)
#pragma unroll
            for (int reg = 0; reg < 4; reg++)
                part[mt][reg] += __shfl_xor(part[mt][reg], off, 64);
    if (l15 == 0) {
#pragma unroll
        for (int mt = 0; mt < 2; mt++)
#pragma unroll
            for (int reg = 0; reg < 4; reg++) {
                int er = eb + wid * 32 + mt * 16 + q * 4 + reg;
                if (er < E2P) {
                    float xr = part[mt][reg] + b2s;
                    wsym2[er] = 0.8f / (1.0f + __expf(-xr));   // sorted index
                }
            }
    }
}

// ======== BP: node-centric, gather-in / coalesced-out, LDS slot cache ========

// single-direction symmetric K-product: f[d] = sum_c m[c]*exp(w*Rs[c][d]), 36 exps
__device__ __forceinline__ void kprod1(const float* __restrict__ RsL, float w,
                                       const float* m, float* f) {
#pragma unroll
    for (int d = 0; d < 8; d++) f[d] = 0.f;
#pragma unroll
    for (int c = 0; c < 8; c++) {
        {
            float kv = __expf(w * RsL[c * 8 + c]);
            f[c] += m[c] * kv;
        }
#pragma unroll
        for (int d = c + 1; d < 8; d++) {
            float kv = __expf(w * RsL[c * 8 + d]);
            f[d] += m[c] * kv;
            f[c] += m[d] * kv;
        }
    }
}

// init (sorted pair i): slot tables {wnS, ppos, M} + logfA in OUTGOING layout
// Slot sl in u's segment = incoming edge (v->u); M[sl] = m(u->v); lf[sl] = logf(M[sl]).
__global__ __launch_bounds__(256) void k_init(const int2* __restrict__ eiS,
        const float* __restrict__ wsym2, const float* __restrict__ degc,
        const float* __restrict__ Rs, const float* __restrict__ Z,
        const int* __restrict__ pos, const int* __restrict__ order,
        float2* __restrict__ wnS, int* __restrict__ ppos,
        _Float16* __restrict__ M, _Float16* __restrict__ logfA) {
    __shared__ float RsL[64];
    const int tid = threadIdx.x;
    if (tid < 64) RsL[tid] = Rs[tid];
    __syncthreads();
    int i = xcd_swz(blockIdx.x, EBLK) * 256 + tid;
    if (i >= E2P) return;
    int p = order[i];
    int2 sd = eiS[i];
    int sp = sd.x, dp = sd.y;
    float w = wsym2[i];
    float nrm = rsqrtf(degc[sp] * degc[dp]);
    int pz0 = pos[p];         // slot of (sp->dp) in dp's segment
    int pz1 = pos[E2P + p];   // slot of (dp->sp) in sp's segment
    wnS[pz0] = make_float2(w, nrm);
    wnS[pz1] = make_float2(w, nrm);
    ppos[pz0] = pz1;
    ppos[pz1] = pz0;
    const f4* Zs = (const f4*)(Z + (size_t)sp * 16);
    const f4* Zd = (const f4*)(Z + (size_t)dp * 16);
    f4 ls0 = Zs[0], ls1 = Zs[1], ld0 = Zd[0], ld1 = Zd[1];
    float lps[8], lpd[8];
#pragma unroll
    for (int u = 0; u < 4; u++) { lps[u] = ls0[u]; lps[4+u] = ls1[u]; lpd[u] = ld0[u]; lpd[4+u] = ld1[u]; }
    float me[8], mr[8];
    {
        float mx = lps[0], mx2 = lpd[0];
#pragma unroll
        for (int d = 1; d < 8; d++) { mx = fmaxf(mx, lps[d]); mx2 = fmaxf(mx2, lpd[d]); }
        float s = 0.f, s2 = 0.f;
#pragma unroll
        for (int d = 0; d < 8; d++) { me[d] = __expf(lps[d] - mx); s += me[d];
                                      mr[d] = __expf(lpd[d] - mx2); s2 += mr[d]; }
        float rs = 1.f / s, rs2 = 1.f / s2;
#pragma unroll
        for (int d = 0; d < 8; d++) { me[d] *= rs; mr[d] *= rs2; }
    }
    {
        h8 mh, mh2;
#pragma unroll
        for (int d = 0; d < 8; d++) { mh[d] = (_Float16)me[d]; mh2[d] = (_Float16)mr[d]; }
        *(h8*)(M + (size_t)pz1 * 8) = mh;    // m(sp->dp) at sp's slot
        *(h8*)(M + (size_t)pz0 * 8) = mh2;   // m(dp->sp) at dp's slot
    }
    float fe[8], fr[8];
    kprod1(RsL, w, me, fe);
    kprod1(RsL, w, mr, fr);
    h8 le, lr;
#pragma unroll
    for (int d = 0; d < 8; d++) {
        le[d] = (_Float16)(__logf(fmaxf(fe[d], 1e-12f)) * nrm);
        lr[d] = (_Float16)(__logf(fmaxf(fr[d], 1e-12f)) * nrm);
    }
    *(h8*)(logfA + (size_t)pz1 * 8) = le;   // OUTGOING layout: lf(sp->dp) at sp's slot
    *(h8*)(logfA + (size_t)pz0 * 8) = lr;   // lf(dp->sp) at dp's slot
}

// fused BP step: block owns 32 nodes. Phase 1a: gather incoming lf (lfP[ppos]) -> LDS.
// Phase 1b: per-node S from LDS + butterfly. Phase 2: flat balanced slot loop;
// exclusion from LDS; M and lfO writes COALESCED (own slot).
__global__ __launch_bounds__(256) void k_bpN(const float* __restrict__ Rs,
        const float* __restrict__ Z, const int* __restrict__ base,
        const float2* __restrict__ wnS, const int* __restrict__ ppos,
        _Float16* __restrict__ M, const _Float16* __restrict__ lfP,
        _Float16* __restrict__ lfO) {
    __shared__ float RsL[64];
    __shared__ int   segs[33];
    __shared__ float ZL[32][8];
    __shared__ float SL[32][8];
    __shared__ _Float16 lfL[BCAP][8];
    __shared__ unsigned char nlL[BCAP];
    const int tid = threadIdx.x;
    const int n0 = xcd_swz(blockIdx.x, gridDim.x) * 32;
    if (tid < 64) RsL[tid] = Rs[tid];
    if (tid < 33) segs[tid] = base[n0 + tid];
    if (tid >= 64 && tid < 96) {
        int nl = tid - 64;
        if (n0 + nl < NN) {
            const f4* zp = (const f4*)(Z + (size_t)(n0 + nl) * 16);
            f4 a = zp[0], b2 = zp[1];
#pragma unroll
            for (int u = 0; u < 4; u++) { ZL[nl][u] = a[u]; ZL[nl][4 + u] = b2[u]; }
        }
    }
    __syncthreads();
    const int s0 = segs[0];
    const int count = segs[32] - s0;
    const float alpha = Rs[64];
    // phase 1a: gather incoming lf into LDS (scattered reads, deep MLP)
    for (int k = tid; k < count; k += 256) {
        int pp = ppos[s0 + k];
        h8 v = *(const h8*)(lfP + (size_t)pp * 8);
        if (k < BCAP) *(h8*)&lfL[k][0] = v;
    }
    __syncthreads();
    // phase 1b: per-node S (8 threads/node) + local-node-index table
    {
        const int nl = tid >> 3, j = tid & 7;
        const int sb = segs[nl] - s0;
        const int cnt = segs[nl + 1] - segs[nl];
        float S[8];
#pragma unroll
        for (int d = 0; d < 8; d++) S[d] = 0.f;
        for (int s = j; s < cnt; s += 8) {
            int k = sb + s;
            h8 v;
            if (k < BCAP) { v = *(h8*)&lfL[k][0]; nlL[k] = (unsigned char)nl; }
            else          { v = *(const h8*)(lfP + (size_t)ppos[s0 + k] * 8); }
#pragma unroll
            for (int d = 0; d < 8; d++) S[d] += (float)v[d];
        }
#pragma unroll
        for (int off = 1; off < 8; off <<= 1)
#pragma unroll
            for (int d = 0; d < 8; d++) S[d] += __shfl_xor(S[d], off, 64);
        SL[nl][j] = S[j];
    }
    __syncthreads();
    // phase 2: flat balanced slot loop, coalesced state I/O
    for (int k = tid; k < count; k += 256) {
        const int sl = s0 + k;
        int nl;
        h8 lfh;
        if (k < BCAP) { nl = nlL[k]; lfh = *(h8*)&lfL[k][0]; }
        else {
            nl = 0;
            for (int a2 = 1; a2 < 32; a2++) if (segs[a2] <= sl) nl = a2;
            lfh = *(const h8*)(lfP + (size_t)ppos[sl] * 8);
        }
        h8 mh = *(const h8*)(M + (size_t)sl * 8);
        float2 wn = wnS[sl];
        float t[8], m1[8];
#pragma unroll
        for (int d = 0; d < 8; d++)
            t[d] = ZL[nl][d] + alpha * (SL[nl][d] - (float)lfh[d]);
        float mx = t[0];
#pragma unroll
        for (int d = 1; d < 8; d++) mx = fmaxf(mx, t[d]);
        float ssum = 0.f;
#pragma unroll
        for (int d = 0; d < 8; d++) { m1[d] = __expf(t[d] - mx); ssum += m1[d]; }
        float rs = 1.f / ssum, t1 = 0.f;
#pragma unroll
        for (int d = 0; d < 8; d++) {
            m1[d] = fmaxf(0.8f * (float)mh[d] + 0.2f * m1[d] * rs, 1e-12f);
            t1 += m1[d];
        }
        float rt = 1.f / t1;
#pragma unroll
        for (int d = 0; d < 8; d++) m1[d] *= rt;
        h8 mo;
#pragma unroll
        for (int d = 0; d < 8; d++) mo[d] = (_Float16)m1[d];
        *(h8*)(M + (size_t)sl * 8) = mo;
        float f2[8];
        kprod1(RsL, wn.x, m1, f2);
        h8 le;
#pragma unroll
        for (int d = 0; d < 8; d++)
            le[d] = (_Float16)(__logf(fmaxf(f2[d], 1e-12f)) * wn.y);
        *(h8*)(lfO + (size_t)sl * 8) = le;   // coalesced (own slot)
    }
}

// ---------------- final: S via ppos-gather + beliefs = softmax(lp + alpha*S) ----------
__global__ void k_sum(const _Float16* __restrict__ logf, const int* __restrict__ base,
                      const int* __restrict__ deg, const int* __restrict__ ppos,
                      const float* __restrict__ Z, const float* __restrict__ Rs,
                      float* __restrict__ out) {
    int g = blockIdx.x * 256 + threadIdx.x;
    int n = g >> 3;
    if (n >= NN) return;
    int j = threadIdx.x & 7;
    int b = base[n], cnt = deg[n];
    float acc[8];
#pragma unroll
    for (int d = 0; d < 8; d++) acc[d] = 0.f;
    for (int s = j; s < cnt; s += 8) {
        h8 v = *(const h8*)(logf + (size_t)ppos[b + s] * 8);
#pragma unroll
        for (int d = 0; d < 8; d++) acc[d] += (float)v[d];
    }
    int lane = threadIdx.x & 63;
    float v4[4], v2[2], r;
    {
        bool hi = (lane & 4) != 0;
#pragma unroll
        for (int i = 0; i < 4; i++) {
            float send = hi ? acc[i] : acc[i + 4];
            float recv = __shfl_xor(send, 4, 64);
            v4[i] = (hi ? acc[i + 4] : acc[i]) + recv;
        }
    }
    {
        bool hi = (lane & 2) != 0;
#pragma unroll
        for (int i = 0; i < 2; i++) {
            float send = hi ? v4[i] : v4[i + 2];
            float recv = __shfl_xor(send, 2, 64);
            v2[i] = (hi ? v4[i + 2] : v4[i]) + recv;
        }
    }
    {
        bool hi = (lane & 1) != 0;
        float send = hi ? v2[0] : v2[1];
        float recv = __shfl_xor(send, 1, 64);
        r = (hi ? v2[1] : v2[0]) + recv;
    }
    float alpha = Rs[64];
    float v = Z[(size_t)n * 16 + j] + alpha * r;
    float mx = v;
    mx = fmaxf(mx, __shfl_xor(mx, 1, 64));
    mx = fmaxf(mx, __shfl_xor(mx, 2, 64));
    mx = fmaxf(mx, __shfl_xor(mx, 4, 64));
    float ex = __expf(v - mx);
    float s = ex;
    s += __shfl_xor(s, 1, 64); s += __shfl_xor(s, 2, 64); s += __shfl_xor(s, 4, 64);
    out[(size_t)n * 8 + j] = ex / s;
}

extern "C" void kernel_launch(void* const* d_in, const int* in_sizes, int n_in,
                              void* d_out, int out_size, void* d_ws, size_t ws_size,
                              hipStream_t stream) {
    if (ws_size < WS_NEED) return;
    const float* x        = (const float*)d_in[0];
    const int*   ei       = (const int*)d_in[1];
    const float* enc_w1   = (const float*)d_in[3];
    const float* enc_b1   = (const float*)d_in[4];
    const float* enc_w2   = (const float*)d_in[5];
    const float* enc_b2   = (const float*)d_in[6];
    const float* edge_w1  = (const float*)d_in[7];
    const float* edge_b1  = (const float*)d_in[8];
    const float* edge_w2  = (const float*)d_in[9];
    const float* edge_b2  = (const float*)d_in[10];
    const float* R_raw    = (const float*)d_in[11];
    const float* Rsl      = (const float*)d_in[12];
    const float* mlog     = (const float*)d_in[13];

    char* ws = (char*)d_ws;
    _Float16* hf     = (_Float16*)(ws + OFF_HF16);
    _Float16* lfA    = (_Float16*)(ws + OFF_LOGFA);
    _Float16* lfB    = (_Float16*)(ws + OFF_LOGFB);
    float* Zb        = (float*)(ws + OFF_Z);
    int*   deg       = (int*)  (ws + OFF_DEG);
    float* logdeg    = (float*)(ws + OFF_LOGDEG);
    float* degc      = (float*)(ws + OFF_DEGC);
    int*   baseA     = (int*)  (ws + OFF_BASE);
    int*   cnt       = (int*)  (ws + OFF_CNT);
    int*   blk       = (int*)  (ws + OFF_BLK);
    _Float16* Wt     = (_Float16*)(ws + OFF_WT);
    _Float16* Bt     = (_Float16*)(ws + OFF_BT);
    float* Rs        = (float*)(ws + OFF_RS);
    float* wsym2     = (float*)(ws + OFF_WSYM);
    int*   pos       = (int*)  (ws + OFF_POS);
    int*   order     = (int*)  (ws + OFF_ORDER);
    int*   base2     = (int*)  (ws + OFF_BASE2);
    int*   ofs2      = (int*)  (ws + OFF_OFS2);
    int2*  eiS       = (int2*) (ws + OFF_EIS);
    _Float16* Mb     = (_Float16*)(ws + OFF_M);
    float2* wnS      = (float2*)(ws + OFF_WNS);
    int*   ppos      = (int*)  (ws + OFF_PPOS);
    float* outp      = (float*)d_out;

    hipMemsetAsync(deg, 0, (size_t)SCN * 4, stream);
    hipMemsetAsync(ofs2, 0, (size_t)SCN * 4, stream);
    k_deg<<<dim3(EDD / 256), dim3(256), 0, stream>>>(ei, deg, ofs2);
    k_node<<<dim3(NBLK), dim3(256), 0, stream>>>(deg, logdeg, degc);
    k_prep<<<dim3((256 * 512 + 64 * 544 + 65 + 255) / 256), dim3(256), 0, stream>>>(
        enc_w1, edge_w1, R_raw, Rsl, mlog, Wt, Bt, Rs);
    // dst-CSR build (one-time)
    k_scan1<<<dim3(NBLK), dim3(256), 0, stream>>>(deg, cnt /*incl scratch*/, blk);
    k_scan2<<<dim3(1), dim3(256), 0, stream>>>(blk);
    k_scan3<<<dim3(NBLK), dim3(256), 0, stream>>>(cnt, deg, blk, baseA);
    hipMemsetAsync(cnt, 0, (size_t)SCN * 4, stream);
    k_pos<<<dim3(EDD / 256), dim3(256), 0, stream>>>(ei, baseA, cnt, pos);
    // pair locality sort (one-time): key = (src>>10)*1024 | (dst>>6)
    k_scan1<<<dim3(NBLK), dim3(256), 0, stream>>>(ofs2, cnt, blk);
    k_scan2<<<dim3(1), dim3(256), 0, stream>>>(blk);
    k_scan3<<<dim3(NBLK), dim3(256), 0, stream>>>(cnt, ofs2, blk, base2);
    hipMemsetAsync(ofs2, 0, (size_t)SCN * 4, stream);
    k_order<<<dim3(EBLK), dim3(256), 0, stream>>>(ei, base2, ofs2, order);
    k_gath<<<dim3(EBLK), dim3(256), 0, stream>>>(ei, order, eiS);
    // encoder + edge MLP
    k_enc<<<dim3((NN + 63) / 64), dim3(256), 0, stream>>>(x, Wt, enc_b1, hf);
    k_logits<<<dim3(NBLK), dim3(256), 0, stream>>>(hf, enc_w2, enc_b2, Zb);
    k_edge<<<dim3(E2P / 128), dim3(256), 0, stream>>>(eiS, hf, logdeg, Bt, edge_b1,
                                                      edge_w2, edge_b2, wsym2);
    // BP loop (lfA/lfB alias hf — hf is dead from here on)
    k_init<<<dim3(EBLK), dim3(256), 0, stream>>>(eiS, wsym2, degc, Rs, Zb, pos, order,
                                                 wnS, ppos, Mb, lfA);
    _Float16* cur = lfA;
    _Float16* nxt = lfB;
    for (int t = 0; t < 10; t++) {
        k_bpN<<<dim3(NBPN), dim3(256), 0, stream>>>(Rs, Zb, baseA, wnS, ppos,
                                                    Mb, cur, nxt);
        _Float16* tmp = cur; cur = nxt; nxt = tmp;
    }
    k_sum<<<dim3((NN * 8 + 255) / 256), dim3(256), 0, stream>>>(cur, baseA, deg, ppos,
                                                                Zb, Rs, outp);
    (void)in_sizes; (void)n_in; (void)out_size;
}

// Round 9
// 805.363 us; speedup vs baseline: 1.0377x; 1.0377x over previous
//
#include <hip/hip_runtime.h>
#include <cstddef>
#include <cstdint>

typedef _Float16 h4 __attribute__((ext_vector_type(4)));
typedef _Float16 h8 __attribute__((ext_vector_type(8)));
typedef float    f4 __attribute__((ext_vector_type(4)));
typedef int      i4 __attribute__((ext_vector_type(4)));

#define NN      50000
#define IND     512
#define HIDN    256
#define E2P     400000
#define EDD     800000
#define NBLK    196    // scan blocks
#define SCN     50176  // NBLK*256: scan domain (>= NN and >= key space)
#define EBLK    1563   // ceil(E2P/256)

// ---- workspace layout (bytes) ----
// logf (f16 [EDD][8] = 12.8MB) aliases hf (dead after k_edge)
#define OFF_HF16    ((size_t)0)            // 25,600,000  f16 h [NN][256]
#define OFF_LOGF    ((size_t)0)            // 12,800,000  f16 [EDD][8] (CSR order)
#define OFF_Z       ((size_t)25600000)     //  3,200,000  f32 [NN][16]: [0:8]=log_phi, [8:16]=S
#define OFF_DEG     ((size_t)28800000)     //    204,800  int [SCN]
#define OFF_LOGDEG  ((size_t)29004800)     //    200,000  f32
#define OFF_DEGC    ((size_t)29204800)     //    200,000  f32
#define OFF_BASE    ((size_t)29404800)     //    204,800  int [SCN] (dst-CSR scan)
#define OFF_CNT     ((size_t)29609600)     //    204,800  int [SCN] (scan scratch / counters)
#define OFF_BLK     ((size_t)29814400)     //      4,096  int (scan block sums)
#define OFF_WT      ((size_t)29818496)     //    262,144  f16 enc_w1^T
#define OFF_BT      ((size_t)30080640)     //     69,632  f16 edge_w1 perm^T (h8-gather K-order)
#define OFF_RS      ((size_t)30150272)     //        512  f32 Rs[64] + alpha at [64]
#define OFF_WSYM    ((size_t)30150784)     //  1,600,000  f32 [E2P] wsym2 (SORTED pair order)
#define OFF_POS     ((size_t)31750784)     //  3,200,000  int [EDD] CSR slot of each directed edge
#define OFF_ORDER   ((size_t)34950784)     //  1,600,000  int [E2P] pairs sorted by locality key
#define OFF_BASE2   ((size_t)36550784)     //    204,800  int [SCN] (pair-key CSR)
#define OFF_OFS2    ((size_t)36755584)     //    204,800  int [SCN] (counters)
#define OFF_PRC     ((size_t)36960384)     //  6,400,000  int4 [E2P] {sp,dp,pz0,pz1} sorted
#define OFF_WN      ((size_t)43360384)     //  3,200,000  float2 [E2P] {w,nrm} sorted
#define OFF_M       ((size_t)46560384)     // 12,800,000  f16 [E2P][16] packed m (in-place)
#define OFF_EIS     ((size_t)59360384)     //  3,200,000  int2 [E2P] {src,dst} sorted
#define WS_NEED     ((size_t)62560384)

// 2-D locality key: src-bucket (1024 nodes) major, dst-bucket (64 nodes) minor
__device__ __forceinline__ int key2(int s, int d) {
    return ((s >> 10) << 10) | (d >> 6);
}

// bijective XCD-aware block remap: each XCD gets a contiguous chunk
__device__ __forceinline__ int xcd_swz(int bid, int nwg) {
    int q = nwg >> 3, r = nwg & 7;
    int x = bid & 7, idx = bid >> 3;
    return (x < r ? x * (q + 1) : r * (q + 1) + (x - r) * q) + idx;
}

// ---------------- degree count + pair-key count (fused) ----------------
__global__ void k_deg(const int* __restrict__ ei, int* __restrict__ deg,
                      int* __restrict__ cnt2) {
    int e = blockIdx.x * 256 + threadIdx.x;   // grid exact: EDD
    int v = ei[e];
    atomicAdd(&deg[v], 1);
    if (e < E2P) {
        int d = ei[EDD + e];
        atomicAdd(&cnt2[key2(v, d)], 1);
    }
}

__global__ void k_node(const int* __restrict__ deg, float* __restrict__ logdeg,
                       float* __restrict__ degc) {
    int n = blockIdx.x * 256 + threadIdx.x;
    if (n < NN) {
        float d = (float)deg[n];
        logdeg[n] = logf(d + 1.0f);
        degc[n]   = fmaxf(d, 1.0f);
    }
}

// ---------------- SCN-sized prefix-sum (3 tiny kernels, grid = NBLK exact) ------------
__global__ void k_scan1(const int* __restrict__ deg, int* __restrict__ incl,
                        int* __restrict__ blk) {
    __shared__ int sm[256];
    int i = blockIdx.x * 256 + threadIdx.x;
    int v = deg[i];
    sm[threadIdx.x] = v;
    __syncthreads();
    for (int off = 1; off < 256; off <<= 1) {
        int t = (threadIdx.x >= off) ? sm[threadIdx.x - off] : 0;
        __syncthreads();
        sm[threadIdx.x] += t;
        __syncthreads();
    }
    incl[i] = sm[threadIdx.x];
    if (threadIdx.x == 255) blk[blockIdx.x] = sm[255];
}

__global__ void k_scan2(int* __restrict__ blk) {
    __shared__ int sm[256];
    int v = (threadIdx.x < NBLK) ? blk[threadIdx.x] : 0;
    sm[threadIdx.x] = v;
    __syncthreads();
    for (int off = 1; off < 256; off <<= 1) {
        int t = (threadIdx.x >= off) ? sm[threadIdx.x - off] : 0;
        __syncthreads();
        sm[threadIdx.x] += t;
        __syncthreads();
    }
    if (threadIdx.x < NBLK) blk[threadIdx.x] = sm[threadIdx.x];
}

__global__ void k_scan3(const int* __restrict__ incl, const int* __restrict__ deg,
                        const int* __restrict__ blk, int* __restrict__ base) {
    int i = blockIdx.x * 256 + threadIdx.x;
    int off = (blockIdx.x > 0) ? blk[blockIdx.x - 1] : 0;
    base[i] = off + incl[i] - deg[i];
}

// pos[e] = CSR slot of directed edge e within its dst node's segment
__global__ void k_pos(const int* __restrict__ ei, const int* __restrict__ base,
                      int* __restrict__ cnt, int* __restrict__ pos) {
    int e = blockIdx.x * 256 + threadIdx.x;   // grid exact: EDD
    int dstn = ei[EDD + e];
    pos[e] = base[dstn] + atomicAdd(&cnt[dstn], 1);
}

__global__ void k_order(const int* __restrict__ ei, const int* __restrict__ base2,
                        int* __restrict__ ofs2, int* __restrict__ order) {
    int p = blockIdx.x * 256 + threadIdx.x;
    if (p < E2P) {
        int k = key2(ei[p], ei[EDD + p]);
        order[base2[k] + atomicAdd(&ofs2[k], 1)] = p;
    }
}

// eiS[i] = {src,dst} of pair order[i]
__global__ void k_gath(const int* __restrict__ ei, const int* __restrict__ order,
                       int2* __restrict__ eiS) {
    int i = blockIdx.x * 256 + threadIdx.x;
    if (i < E2P) {
        int p = order[i];
        eiS[i] = make_int2(ei[p], ei[EDD + p]);
    }
}

// ---------------- weight prep ----------------
// Bt K-order for h8 gathers: MFMA step tm (0..15), lane q, element e=2j+typ
//   k' = tm*32 + q*8 + 2j + typ  <->  column c = (tm>>1)*32 + q*8 + (tm&1)*4 + j
//   typ 0 = product feature (row c), typ 1 = absdiff (row 256+c). k'=512,513: struct.
__global__ void k_prep(const float* __restrict__ enc_w1, const float* __restrict__ edge_w1,
                       const float* __restrict__ R_raw, const float* __restrict__ Rsl,
                       const float* __restrict__ mlog,
                       _Float16* __restrict__ Wt, _Float16* __restrict__ Bt,
                       float* __restrict__ Rs) {
    int gid = blockIdx.x * 256 + threadIdx.x;
    if (gid < 256 * 512) {                       // Wt[n][k] = enc_w1[k][n]
        int n = gid >> 9, k = gid & 511;
        Wt[n * 512 + k] = (_Float16)enc_w1[k * 256 + n];
        return;
    }
    int g2 = gid - 256 * 512;
    if (g2 < 64 * 544) {                         // Bt[n][k'] with h8-gather K perm
        int n = g2 / 544, k = g2 - n * 544;
        float v = 0.0f;
        if (k < 512) {
            int tm = k >> 5, r = k & 31;
            int qq = r >> 3, jj = (r >> 1) & 3, typ = k & 1;
            int c = (tm >> 1) * 32 + qq * 8 + (tm & 1) * 4 + jj;
            v = edge_w1[(typ ? 256 + c : c) * 64 + n];
        } else if (k < 514) {
            v = edge_w1[k * 64 + n];
        }
        Bt[n * 544 + k] = (_Float16)v;
        return;
    }
    int g3 = g2 - 64 * 544;
    if (g3 < 64) {
        int c = g3 >> 3, d = g3 & 7;
        float rv = 0.5f * (R_raw[c * 8 + d] + R_raw[d * 8 + c]);
        float s  = log1pf(expf(Rsl[0])) + 1e-6f;
        Rs[g3] = s * tanhf(rv);
        return;
    }
    if (g3 == 64) {
        Rs[64] = 1.5f / (1.0f + expf(-mlog[0]));
    }
}

// ---------------- encoder: h = relu(x @ W + b1) AND fused logits+log_softmax ----------
// 64 rows/block, W double-buffered in LDS (round-7 structure, 76 VGPR main loop).
// Epilogue: block already holds h[64][256] in acc regs -> compute Z[row][0:8] directly.
__global__ __launch_bounds__(256) void k_enc(const float* __restrict__ x,
        const _Float16* __restrict__ Wt, const float* __restrict__ b1,
        const float* __restrict__ w2, const float* __restrict__ b2,
        _Float16* __restrict__ hf, float* __restrict__ Z) {
    __shared__ _Float16 WL[2][256 * 40];   // 2 x 20 KB
    const int tid = threadIdx.x;
    const int wid = tid >> 6;
    const int lane = tid & 63;
    const int l15 = lane & 15;
    const int q = lane >> 4;
    const int m0 = blockIdx.x * 64;
    const int row = m0 + wid * 16 + l15;
    const bool ract = (row < NN);
    const float* xrow = x + (size_t)row * IND;

    f4 acc[16];
#pragma unroll
    for (int i = 0; i < 16; i++) acc[i] = (f4){0.f, 0.f, 0.f, 0.f};

    const int wn = tid >> 2;          // staging: W row
    const int wo = (tid & 3) * 8;     // staging: col offset

    // preload kt=0
    h8 wreg[4];
#pragma unroll
    for (int rep = 0; rep < 4; rep++)
        wreg[rep] = *(const h8*)(Wt + (size_t)(rep * 64 + wn) * IND + wo);
    f4 xa = (f4){0, 0, 0, 0}, xb = (f4){0, 0, 0, 0};
    if (ract) {
        const f4* xp = (const f4*)(xrow + q * 8);
        xa = xp[0]; xb = xp[1];
    }

    for (int kt = 0; kt < 16; kt++) {
        const int cur = kt & 1;
#pragma unroll
        for (int rep = 0; rep < 4; rep++)
            *(h8*)&WL[cur][(rep * 64 + wn) * 40 + wo] = wreg[rep];
        __syncthreads();
        f4 xa2, xb2;
        if (kt < 15) {                  // prefetch kt+1 while MFMAs run
            const int kc = (kt + 1) * 32;
#pragma unroll
            for (int rep = 0; rep < 4; rep++)
                wreg[rep] = *(const h8*)(Wt + (size_t)(rep * 64 + wn) * IND + kc + wo);
            if (ract) {
                const f4* xp = (const f4*)(xrow + kc + q * 8);
                xa2 = xp[0]; xb2 = xp[1];
            }
        }
        h8 a;
#pragma unroll
        for (int u = 0; u < 4; u++) { a[u] = (_Float16)xa[u]; a[4 + u] = (_Float16)xb[u]; }
#pragma unroll
        for (int nt = 0; nt < 16; nt++) {
            h8 b = *(const h8*)&WL[cur][(nt * 16 + l15) * 40 + q * 8];
            acc[nt] = __builtin_amdgcn_mfma_f32_16x16x32_f16(a, b, acc[nt], 0, 0, 0);
        }
        if (kt < 15 && ract) { xa = xa2; xb = xb2; }
        __syncthreads();   // protect WL[cur] until all waves' MFMA reads done
    }

    float bv16[16];
#pragma unroll
    for (int nt = 0; nt < 16; nt++) bv16[nt] = b1[nt * 16 + l15];
    // hf store (f16-quantized relu)
#pragma unroll
    for (int nt = 0; nt < 16; nt++) {
        int col = nt * 16 + l15;
#pragma unroll
        for (int reg = 0; reg < 4; reg++) {
            int orow = m0 + wid * 16 + q * 4 + reg;
            if (orow < NN) {
                float v = acc[nt][reg] + bv16[nt];
                hf[(size_t)orow * HIDN + col] = (_Float16)fmaxf(v, 0.f);
            }
        }
    }
    // fused logits: stage w2 (256x8 f32 = 8KB) into dead WL space
    float* w2L = (float*)&WL[0][0];
    __syncthreads();
    for (int i2 = tid; i2 < 2048; i2 += 256) w2L[i2] = w2[i2];
    __syncthreads();
    float lsum[4][8];
#pragma unroll
    for (int r2 = 0; r2 < 4; r2++)
#pragma unroll
        for (int c = 0; c < 8; c++) lsum[r2][c] = 0.f;
#pragma unroll
    for (int nt = 0; nt < 16; nt++) {
        const float* wr = &w2L[(nt * 16 + l15) * 8];
        f4 w0 = *(const f4*)wr;
        f4 w1 = *(const f4*)(wr + 4);
#pragma unroll
        for (int r2 = 0; r2 < 4; r2++) {
            float v = fmaxf(acc[nt][r2] + bv16[nt], 0.f);
            float hx = (float)(_Float16)v;         // match k_logits' f16-read path
#pragma unroll
            for (int c = 0; c < 4; c++) {
                lsum[r2][c]     += hx * w0[c];
                lsum[r2][4 + c] += hx * w1[c];
            }
        }
    }
#pragma unroll
    for (int off = 1; off < 16; off <<= 1)       // reduce over the 16 l15 lanes
#pragma unroll
        for (int r2 = 0; r2 < 4; r2++)
#pragma unroll
            for (int c = 0; c < 8; c++)
                lsum[r2][c] += __shfl_xor(lsum[r2][c], off, 64);
    if (l15 == 0) {
#pragma unroll
        for (int r2 = 0; r2 < 4; r2++) {
            int orow = m0 + wid * 16 + q * 4 + r2;
            if (orow < NN) {
                float s8[8];
#pragma unroll
                for (int c = 0; c < 8; c++) s8[c] = lsum[r2][c] + b2[c];
                float mx = s8[0];
#pragma unroll
                for (int c = 1; c < 8; c++) mx = fmaxf(mx, s8[c]);
                float se = 0.f;
#pragma unroll
                for (int c = 0; c < 8; c++) se += __expf(s8[c] - mx);
                float lse = __logf(se);
                f4 z0, z1;
#pragma unroll
                for (int c = 0; c < 4; c++) {
                    z0[c] = s8[c] - mx - lse;
                    z1[c] = s8[4 + c] - mx - lse;
                }
                *(f4*)(Z + (size_t)orow * 16)     = z0;
                *(f4*)(Z + (size_t)orow * 16 + 4) = z1;
            }
        }
    }
}

// ---------------- edge MLP over locality-sorted pairs + XCD chunking -----------------
__global__ __launch_bounds__(256) void k_edge(const int2* __restrict__ eiS,
        const _Float16* __restrict__ hf, const float* __restrict__ logdeg,
        const _Float16* __restrict__ BtG, const float* __restrict__ eb1,
        const float* __restrict__ ew2, const float* __restrict__ eb2,
        float* __restrict__ wsym2) {
    __shared__ _Float16 BtL[64 * 136];
    const int tid = threadIdx.x;
    const int wid = tid >> 6;
    const int lane = tid & 63;
    const int l15 = lane & 15;
    const int q = lane >> 4;
    const int eb = xcd_swz(blockIdx.x, gridDim.x) * 128;  // grid exact: E2P/128 = 3125

    int sidx[2], didx[2];
    float la[2], lb[2];
#pragma unroll
    for (int mt = 0; mt < 2; mt++) {
        int e = eb + wid * 32 + mt * 16 + l15;   // always < E2P
        int2 sd = eiS[e];
        sidx[mt] = sd.x;
        didx[mt] = sd.y;
        la[mt] = logdeg[sidx[mt]];
        lb[mt] = logdeg[didx[mt]];
    }

    f4 acc[2][4];
#pragma unroll
    for (int a = 0; a < 2; a++)
#pragma unroll
        for (int b = 0; b < 4; b++) acc[a][b] = (f4){0.f, 0.f, 0.f, 0.f};

    const _Float16* hq = hf + q * 8;            // lane's 16B column slice
    h8 curS[2], curD[2];
#pragma unroll
    for (int mt = 0; mt < 2; mt++) {            // kk=0 fragments (cols q*8..q*8+7)
        curS[mt] = *(const h8*)(hq + (size_t)sidx[mt] * HIDN);
        curD[mt] = *(const h8*)(hq + (size_t)didx[mt] * HIDN);
    }

    for (int ph = 0; ph < 4; ph++) {
        __syncthreads();
        {   // stage 64 rows x 128 cols of Bt (r=tid>>2 mapping: conflict-free writes)
            const int r = tid >> 2;
            const int c0 = tid & 3;
            const int kbase = ph * 128;
#pragma unroll
            for (int i2 = 0; i2 < 4; i2++) {
                int ck = c0 + i2 * 4;
                *(h8*)&BtL[r * 136 + ck * 8] =
                    *(const h8*)(BtG + (size_t)r * 544 + kbase + ck * 8);
            }
        }
        __syncthreads();
#pragma unroll
        for (int kk2 = 0; kk2 < 2; kk2++) {
            const int kk = ph * 2 + kk2;
            h8 nxtS[2], nxtD[2];
            if (kk < 7) {                        // prefetch next 16B slice
                const int c1 = (kk + 1) * 32;
#pragma unroll
                for (int mt = 0; mt < 2; mt++) {
                    nxtS[mt] = *(const h8*)(hq + (size_t)sidx[mt] * HIDN + c1);
                    nxtD[mt] = *(const h8*)(hq + (size_t)didx[mt] * HIDN + c1);
                }
            }
            const int ko = kk2 * 64 + q * 8;
            // half 0 (cols +0..3)
            {
                h8 a0[2];
#pragma unroll
                for (int mt = 0; mt < 2; mt++) {
#pragma unroll
                    for (int j = 0; j < 4; j++) {
                        float x1 = (float)curS[mt][j], x2 = (float)curD[mt][j];
                        a0[mt][2 * j]     = (_Float16)(x1 * x2);
                        a0[mt][2 * j + 1] = (_Float16)fabsf(x1 - x2);
                    }
                }
                h8 bf[4];
#pragma unroll
                for (int nt = 0; nt < 4; nt++)
                    bf[nt] = *(const h8*)&BtL[(nt * 16 + l15) * 136 + ko];
#pragma unroll
                for (int mt = 0; mt < 2; mt++)
#pragma unroll
                    for (int nt = 0; nt < 4; nt++)
                        acc[mt][nt] = __builtin_amdgcn_mfma_f32_16x16x32_f16(a0[mt], bf[nt], acc[mt][nt], 0, 0, 0);
            }
            // half 1 (cols +4..7)
            {
                h8 a1[2];
#pragma unroll
                for (int mt = 0; mt < 2; mt++) {
#pragma unroll
                    for (int j = 0; j < 4; j++) {
                        float x1 = (float)curS[mt][4 + j], x2 = (float)curD[mt][4 + j];
                        a1[mt][2 * j]     = (_Float16)(x1 * x2);
                        a1[mt][2 * j + 1] = (_Float16)fabsf(x1 - x2);
                    }
                }
                h8 bf[4];
#pragma unroll
                for (int nt = 0; nt < 4; nt++)
                    bf[nt] = *(const h8*)&BtL[(nt * 16 + l15) * 136 + ko + 32];
#pragma unroll
                for (int mt = 0; mt < 2; mt++)
#pragma unroll
                    for (int nt = 0; nt < 4; nt++)
                        acc[mt][nt] = __builtin_amdgcn_mfma_f32_16x16x32_f16(a1[mt], bf[nt], acc[mt][nt], 0, 0, 0);
            }
            if (kk < 7) {
#pragma unroll
                for (int mt = 0; mt < 2; mt++) { curS[mt] = nxtS[mt]; curD[mt] = nxtD[mt]; }
            }
        }
    }

    // struct features step (k' = 512..543, only 512/513 nonzero)
    __syncthreads();
    {
        const int r = tid >> 2, ck = tid & 3;
        *(h8*)&BtL[r * 136 + ck * 8] = *(const h8*)(BtG + (size_t)r * 544 + 512 + ck * 8);
    }
    __syncthreads();
    {
        h8 bf[4];
#pragma unroll
        for (int nt = 0; nt < 4; nt++)
            bf[nt] = *(const h8*)&BtL[(nt * 16 + l15) * 136 + q * 8];
#pragma unroll
        for (int mt = 0; mt < 2; mt++) {
            h8 a = (h8){0, 0, 0, 0, 0, 0, 0, 0};
            if (q == 0) {
                a[0] = (_Float16)(la[mt] + lb[mt]);
                a[1] = (_Float16)fabsf(la[mt] - lb[mt]);
            }
#pragma unroll
            for (int nt = 0; nt < 4; nt++)
                acc[mt][nt] = __builtin_amdgcn_mfma_f32_16x16x32_f16(a, bf[nt], acc[mt][nt], 0, 0, 0);
        }
    }

    float b1v[4], w2v[4];
#pragma unroll
    for (int nt = 0; nt < 4; nt++) {
        int col = nt * 16 + l15;
        b1v[nt] = eb1[col];
        w2v[nt] = ew2[col];
    }
    const float b2s = eb2[0];
    float part[2][4];
#pragma unroll
    for (int mt = 0; mt < 2; mt++)
#pragma unroll
        for (int reg = 0; reg < 4; reg++) {
            float s = 0.f;
#pragma unroll
            for (int nt = 0; nt < 4; nt++) {
                float v = acc[mt][nt][reg] + b1v[nt];
                s += fmaxf(v, 0.f) * w2v[nt];
            }
            part[mt][reg] = s;
        }
#pragma unroll
    for (int off = 1; off < 16; off <<= 1)
#pragma unroll
        for (int mt = 0; mt < 2; mt++)
#pragma unroll
            for (int reg = 0; reg < 4; reg++)
                part[mt][reg] += __shfl_xor(part[mt][reg], off, 64);
    if (l15 == 0) {
#pragma unroll
        for (int mt = 0; mt < 2; mt++)
#pragma unroll
            for (int reg = 0; reg < 4; reg++) {
                int er = eb + wid * 32 + mt * 16 + q * 4 + reg;
                if (er < E2P) {
                    float xr = part[mt][reg] + b2s;
                    wsym2[er] = 0.8f / (1.0f + __expf(-xr));   // sorted index
                }
            }
    }
}

// ======== BP: locality-sorted pairs; packed state; kprod-recompute exclusion ========

// symmetric K-product: f = m @ exp(w*Rs), 36 unique exps (Rs symmetric)
__device__ __forceinline__ void kprod(const float* __restrict__ RsL, float w,
                                      const float* me, const float* mr,
                                      float* fe, float* fr) {
#pragma unroll
    for (int d = 0; d < 8; d++) { fe[d] = 0.f; fr[d] = 0.f; }
#pragma unroll
    for (int c = 0; c < 8; c++) {
        {
            float kv = __expf(w * RsL[c * 8 + c]);
            fe[c] += me[c] * kv;
            fr[c] += mr[c] * kv;
        }
#pragma unroll
        for (int d = c + 1; d < 8; d++) {
            float kv = __expf(w * RsL[c * 8 + d]);
            fe[d] += me[c] * kv; fr[d] += mr[c] * kv;
            fe[c] += me[d] * kv; fr[c] += mr[d] * kv;
        }
    }
}

// init (sorted index i): write packed state + m + logf
__global__ __launch_bounds__(256) void k_init(const int2* __restrict__ eiS,
        const float* __restrict__ wsym2, const float* __restrict__ degc,
        const float* __restrict__ Rs, const float* __restrict__ Z,
        const int* __restrict__ pos, const int* __restrict__ order,
        i4* __restrict__ prc, float2* __restrict__ wn,
        _Float16* __restrict__ M, _Float16* __restrict__ logf) {
    __shared__ float RsL[64];
    const int tid = threadIdx.x;
    if (tid < 64) RsL[tid] = Rs[tid];
    __syncthreads();
    int i = xcd_swz(blockIdx.x, EBLK) * 256 + tid;
    if (i >= E2P) return;
    int p = order[i];
    int2 sd = eiS[i];
    int sp = sd.x, dp = sd.y;
    float w = wsym2[i];
    float nrm = rsqrtf(degc[sp] * degc[dp]);
    int pz0 = pos[p], pz1 = pos[E2P + p];
    prc[i] = (i4){sp, dp, pz0, pz1};
    wn[i] = make_float2(w, nrm);
    const f4* Zs = (const f4*)(Z + (size_t)sp * 16);
    const f4* Zd = (const f4*)(Z + (size_t)dp * 16);
    f4 ls0 = Zs[0], ls1 = Zs[1], ld0 = Zd[0], ld1 = Zd[1];
    float lps[8], lpd[8];
#pragma unroll
    for (int u = 0; u < 4; u++) { lps[u] = ls0[u]; lps[4+u] = ls1[u]; lpd[u] = ld0[u]; lpd[4+u] = ld1[u]; }
    float me[8], mr[8];
    {
        float mx = lps[0], mx2 = lpd[0];
#pragma unroll
        for (int d = 1; d < 8; d++) { mx = fmaxf(mx, lps[d]); mx2 = fmaxf(mx2, lpd[d]); }
        float s = 0.f, s2 = 0.f;
#pragma unroll
        for (int d = 0; d < 8; d++) { me[d] = __expf(lps[d] - mx); s += me[d];
                                      mr[d] = __expf(lpd[d] - mx2); s2 += mr[d]; }
        float rs = 1.f / s, rs2 = 1.f / s2;
#pragma unroll
        for (int d = 0; d < 8; d++) { me[d] *= rs; mr[d] *= rs2; }
    }
    {
        h8 mh, mh2;
#pragma unroll
        for (int d = 0; d < 8; d++) { mh[d] = (_Float16)me[d]; mh2[d] = (_Float16)mr[d]; }
        *(h8*)(M + (size_t)i * 16)     = mh;
        *(h8*)(M + (size_t)i * 16 + 8) = mh2;
    }
    float fe[8], fr[8];
    kprod(RsL, w, me, mr, fe, fr);
    h8 le, lr;
#pragma unroll
    for (int d = 0; d < 8; d++) {
        le[d] = (_Float16)(__logf(fmaxf(fe[d], 1e-12f)) * nrm);
        lr[d] = (_Float16)(__logf(fmaxf(fr[d], 1e-12f)) * nrm);
    }
    *(h8*)(logf + (size_t)pz0 * 8) = le;   // -> dp's segment
    *(h8*)(logf + (size_t)pz1 * 8) = lr;   // -> sp's segment
}

// fused BP step (sorted index i): exclusion via kprod recompute (verified config)
__global__ __launch_bounds__(256) void k_bpF(const i4* __restrict__ prc,
        const float2* __restrict__ wn, const float* __restrict__ Rs,
        const float* __restrict__ Z, _Float16* __restrict__ M,
        _Float16* __restrict__ logf) {
    __shared__ float RsL[64];
    const int tid = threadIdx.x;
    if (tid < 64) RsL[tid] = Rs[tid];
    __syncthreads();
    int i = xcd_swz(blockIdx.x, EBLK) * 256 + tid;
    if (i >= E2P) return;
    i4 c4 = prc[i];
    const int sp = c4[0], dp = c4[1], pz0 = c4[2], pz1 = c4[3];
    float2 wnv = wn[i];
    const float w = wnv.x, nrm = wnv.y;
    const float alpha = Rs[64];
    h8 mhe = *(const h8*)(M + (size_t)i * 16);
    h8 mhr = *(const h8*)(M + (size_t)i * 16 + 8);
    float me[8], mr[8];
#pragma unroll
    for (int d = 0; d < 8; d++) { me[d] = (float)mhe[d]; mr[d] = (float)mhr[d]; }
    float fe[8], fr[8];
    kprod(RsL, w, me, mr, fe, fr);
    float lfe[8], lfr[8];
#pragma unroll
    for (int d = 0; d < 8; d++) {
        lfe[d] = __logf(fmaxf(fe[d], 1e-12f)) * nrm;
        lfr[d] = __logf(fmaxf(fr[d], 1e-12f)) * nrm;
    }
    const f4* Zs = (const f4*)(Z + (size_t)sp * 16);
    const f4* Zd = (const f4*)(Z + (size_t)dp * 16);
    f4 ls0 = Zs[0], ls1 = Zs[1], ss0 = Zs[2], ss1 = Zs[3];
    f4 ld0 = Zd[0], ld1 = Zd[1], sd0 = Zd[2], sd1 = Zd[3];
    float te[8], tr[8];
#pragma unroll
    for (int u = 0; u < 4; u++) {
        te[u]     = ls0[u] + alpha * (ss0[u] - lfr[u]);
        te[4 + u] = ls1[u] + alpha * (ss1[u] - lfr[4 + u]);
        tr[u]     = ld0[u] + alpha * (sd0[u] - lfe[u]);
        tr[4 + u] = ld1[u] + alpha * (sd1[u] - lfe[4 + u]);
    }
    float m1[8], m2[8];
    {
        float mx = te[0], mx2 = tr[0];
#pragma unroll
        for (int d = 1; d < 8; d++) { mx = fmaxf(mx, te[d]); mx2 = fmaxf(mx2, tr[d]); }
        float s = 0.f, s2 = 0.f;
#pragma unroll
        for (int d = 0; d < 8; d++) { m1[d] = __expf(te[d] - mx); s += m1[d];
                                      m2[d] = __expf(tr[d] - mx2); s2 += m2[d]; }
        float rs = 1.f / s, rs2 = 1.f / s2;
        float t1 = 0.f, t2 = 0.f;
#pragma unroll
        for (int d = 0; d < 8; d++) {
            m1[d] = fmaxf(0.8f * me[d] + 0.2f * m1[d] * rs, 1e-12f);  t1 += m1[d];
            m2[d] = fmaxf(0.8f * mr[d] + 0.2f * m2[d] * rs2, 1e-12f); t2 += m2[d];
        }
        float rt1 = 1.f / t1, rt2 = 1.f / t2;
#pragma unroll
        for (int d = 0; d < 8; d++) { m1[d] *= rt1; m2[d] *= rt2; }
    }
    {
        h8 mh, mh2;
#pragma unroll
        for (int d = 0; d < 8; d++) { mh[d] = (_Float16)m1[d]; mh2[d] = (_Float16)m2[d]; }
        *(h8*)(M + (size_t)i * 16)     = mh;
        *(h8*)(M + (size_t)i * 16 + 8) = mh2;
    }
    // new log_f for next iteration's sum
    float fe2[8], fr2[8];
    kprod(RsL, w, m1, m2, fe2, fr2);
    h8 le, lr;
#pragma unroll
    for (int d = 0; d < 8; d++) {
        le[d] = (_Float16)(__logf(fmaxf(fe2[d], 1e-12f)) * nrm);
        lr[d] = (_Float16)(__logf(fmaxf(fr2[d], 1e-12f)) * nrm);
    }
    *(h8*)(logf + (size_t)pz0 * 8) = le;
    *(h8*)(logf + (size_t)pz1 * 8) = lr;
}

// ---------------- sum_in: CSR reduction, h8 loads + 8-lane fold-reduce ----------------
// fin==0: write S to Z[n][8+j].  fin==1: beliefs = softmax(log_phi + alpha*S) -> out.
__global__ void k_sum(const _Float16* __restrict__ logf, const int* __restrict__ base,
                      const int* __restrict__ deg, float* __restrict__ Z,
                      const float* __restrict__ Rs, float* __restrict__ out, int fin) {
    int g = blockIdx.x * 256 + threadIdx.x;
    int n = g >> 3;
    if (n >= NN) return;
    int j = threadIdx.x & 7;
    int b = base[n], cnt = deg[n];
    float acc[8];
#pragma unroll
    for (int d = 0; d < 8; d++) acc[d] = 0.f;
    for (int s = j; s < cnt; s += 8) {
        h8 v = *(const h8*)(logf + (size_t)(b + s) * 8);
#pragma unroll
        for (int d = 0; d < 8; d++) acc[d] += (float)v[d];
    }
    int lane = threadIdx.x & 63;
    float v4[4], v2[2], r;
    {
        bool hi = (lane & 4) != 0;
#pragma unroll
        for (int i = 0; i < 4; i++) {
            float send = hi ? acc[i] : acc[i + 4];
            float recv = __shfl_xor(send, 4, 64);
            v4[i] = (hi ? acc[i + 4] : acc[i]) + recv;
        }
    }
    {
        bool hi = (lane & 2) != 0;
#pragma unroll
        for (int i = 0; i < 2; i++) {
            float send = hi ? v4[i] : v4[i + 2];
            float recv = __shfl_xor(send, 2, 64);
            v2[i] = (hi ? v4[i + 2] : v4[i]) + recv;
        }
    }
    {
        bool hi = (lane & 1) != 0;
        float send = hi ? v2[0] : v2[1];
        float recv = __shfl_xor(send, 1, 64);
        r = (hi ? v2[1] : v2[0]) + recv;
    }
    if (!fin) {
        Z[(size_t)n * 16 + 8 + j] = r;
    } else {
        float alpha = Rs[64];
        float v = Z[(size_t)n * 16 + j] + alpha * r;
        float mx = v;
        mx = fmaxf(mx, __shfl_xor(mx, 1, 64));
        mx = fmaxf(mx, __shfl_xor(mx, 2, 64));
        mx = fmaxf(mx, __shfl_xor(mx, 4, 64));
        float ex = __expf(v - mx);
        float s = ex;
        s += __shfl_xor(s, 1, 64); s += __shfl_xor(s, 2, 64); s += __shfl_xor(s, 4, 64);
        out[(size_t)n * 8 + j] = ex / s;
    }
}

extern "C" void kernel_launch(void* const* d_in, const int* in_sizes, int n_in,
                              void* d_out, int out_size, void* d_ws, size_t ws_size,
                              hipStream_t stream) {
    if (ws_size < WS_NEED) return;
    const float* x        = (const float*)d_in[0];
    const int*   ei       = (const int*)d_in[1];
    const float* enc_w1   = (const float*)d_in[3];
    const float* enc_b1   = (const float*)d_in[4];
    const float* enc_w2   = (const float*)d_in[5];
    const float* enc_b2   = (const float*)d_in[6];
    const float* edge_w1  = (const float*)d_in[7];
    const float* edge_b1  = (const float*)d_in[8];
    const float* edge_w2  = (const float*)d_in[9];
    const float* edge_b2  = (const float*)d_in[10];
    const float* R_raw    = (const float*)d_in[11];
    const float* Rsl      = (const float*)d_in[12];
    const float* mlog     = (const float*)d_in[13];

    char* ws = (char*)d_ws;
    _Float16* hf     = (_Float16*)(ws + OFF_HF16);
    _Float16* logfb  = (_Float16*)(ws + OFF_LOGF);
    float* Zb        = (float*)(ws + OFF_Z);
    int*   deg       = (int*)  (ws + OFF_DEG);
    float* logdeg    = (float*)(ws + OFF_LOGDEG);
    float* degc      = (float*)(ws + OFF_DEGC);
    int*   baseA     = (int*)  (ws + OFF_BASE);
    int*   cnt       = (int*)  (ws + OFF_CNT);
    int*   blk       = (int*)  (ws + OFF_BLK);
    _Float16* Wt     = (_Float16*)(ws + OFF_WT);
    _Float16* Bt     = (_Float16*)(ws + OFF_BT);
    float* Rs        = (float*)(ws + OFF_RS);
    float* wsym2     = (float*)(ws + OFF_WSYM);
    int*   pos       = (int*)  (ws + OFF_POS);
    int*   order     = (int*)  (ws + OFF_ORDER);
    int*   base2     = (int*)  (ws + OFF_BASE2);
    int*   ofs2      = (int*)  (ws + OFF_OFS2);
    i4*    prc       = (i4*)   (ws + OFF_PRC);
    float2* wnb      = (float2*)(ws + OFF_WN);
    _Float16* Mb     = (_Float16*)(ws + OFF_M);
    int2*  eiS       = (int2*) (ws + OFF_EIS);
    float* outp      = (float*)d_out;

    hipMemsetAsync(deg, 0, (size_t)SCN * 4, stream);
    hipMemsetAsync(ofs2, 0, (size_t)SCN * 4, stream);
    k_deg<<<dim3(EDD / 256), dim3(256), 0, stream>>>(ei, deg, ofs2);
    k_node<<<dim3(NBLK), dim3(256), 0, stream>>>(deg, logdeg, degc);
    k_prep<<<dim3((256 * 512 + 64 * 544 + 65 + 255) / 256), dim3(256), 0, stream>>>(
        enc_w1, edge_w1, R_raw, Rsl, mlog, Wt, Bt, Rs);
    // dst-CSR build (one-time)
    k_scan1<<<dim3(NBLK), dim3(256), 0, stream>>>(deg, cnt /*incl scratch*/, blk);
    k_scan2<<<dim3(1), dim3(256), 0, stream>>>(blk);
    k_scan3<<<dim3(NBLK), dim3(256), 0, stream>>>(cnt, deg, blk, baseA);
    hipMemsetAsync(cnt, 0, (size_t)SCN * 4, stream);
    k_pos<<<dim3(EDD / 256), dim3(256), 0, stream>>>(ei, baseA, cnt, pos);
    // pair locality sort (one-time): key = (src>>10)*1024 | (dst>>6)
    k_scan1<<<dim3(NBLK), dim3(256), 0, stream>>>(ofs2, cnt, blk);
    k_scan2<<<dim3(1), dim3(256), 0, stream>>>(blk);
    k_scan3<<<dim3(NBLK), dim3(256), 0, stream>>>(cnt, ofs2, blk, base2);
    hipMemsetAsync(ofs2, 0, (size_t)SCN * 4, stream);
    k_order<<<dim3(EBLK), dim3(256), 0, stream>>>(ei, base2, ofs2, order);
    k_gath<<<dim3(EBLK), dim3(256), 0, stream>>>(ei, order, eiS);
    // encoder (with fused logits) + edge MLP
    k_enc<<<dim3((NN + 63) / 64), dim3(256), 0, stream>>>(x, Wt, enc_b1, enc_w2, enc_b2,
                                                          hf, Zb);
    k_edge<<<dim3(E2P / 128), dim3(256), 0, stream>>>(eiS, hf, logdeg, Bt, edge_b1,
                                                      edge_w2, edge_b2, wsym2);
    // BP loop (logfb aliases hf — hf is dead from here on)
    k_init<<<dim3(EBLK), dim3(256), 0, stream>>>(eiS, wsym2, degc, Rs, Zb, pos, order,
                                                 prc, wnb, Mb, logfb);
    k_sum<<<dim3((NN * 8 + 255) / 256), dim3(256), 0, stream>>>(logfb, baseA, deg, Zb,
                                                                Rs, outp, 0);
    for (int t = 0; t < 10; t++) {
        k_bpF<<<dim3(EBLK), dim3(256), 0, stream>>>(prc, wnb, Rs, Zb, Mb, logfb);
        k_sum<<<dim3((NN * 8 + 255) / 256), dim3(256), 0, stream>>>(logfb, baseA, deg, Zb,
                                                                    Rs, outp, (t == 9) ? 1 : 0);
    }
    (void)in_sizes; (void)n_in; (void)out_size;
}

// Round 10
// 797.160 us; speedup vs baseline: 1.0484x; 1.0103x over previous
//
#include <hip/hip_runtime.h>
#include <cstddef>
#include <cstdint>

typedef _Float16 h4 __attribute__((ext_vector_type(4)));
typedef _Float16 h8 __attribute__((ext_vector_type(8)));
typedef float    f4 __attribute__((ext_vector_type(4)));
typedef int      i4 __attribute__((ext_vector_type(4)));

#define NN      50000
#define IND     512
#define HIDN    256
#define E2P     400000
#define EDD     800000
#define NBLK    196    // scan blocks
#define SCN     50176  // NBLK*256: scan domain (>= NN and >= key space)
#define EBLK    1563   // ceil(E2P/256)

// ---- workspace layout (bytes) ----
// logf (f16 [EDD][8] = 12.8MB) aliases hf (dead after k_edge)
#define OFF_HF16    ((size_t)0)            // 25,600,000  f16 h [NN][256]
#define OFF_LOGF    ((size_t)0)            // 12,800,000  f16 [EDD][8] (CSR order)
#define OFF_Z       ((size_t)25600000)     //  3,200,000  f32 [NN][16]: [0:8]=log_phi, [8:16]=S
#define OFF_DEG     ((size_t)28800000)     //    204,800  int [SCN]
#define OFF_LOGDEG  ((size_t)29004800)     //    200,000  f32
#define OFF_DEGC    ((size_t)29204800)     //    200,000  f32
#define OFF_BASE    ((size_t)29404800)     //    204,800  int [SCN] (dst-CSR scan)
#define OFF_CNT     ((size_t)29609600)     //    204,800  int [SCN] (scan scratch / counters)
#define OFF_BLK     ((size_t)29814400)     //      4,096  int (scan block sums)
#define OFF_WT      ((size_t)29818496)     //    262,144  f16 enc_w1^T
#define OFF_BT      ((size_t)30080640)     //     69,632  f16 edge_w1 perm^T (h8-gather K-order)
#define OFF_RS      ((size_t)30150272)     //        512  f32 Rs[64] + alpha at [64]
#define OFF_WSYM    ((size_t)30150784)     //  1,600,000  f32 [E2P] wsym2 (SORTED pair order)
#define OFF_POS     ((size_t)31750784)     //  3,200,000  int [EDD] CSR slot of each directed edge
#define OFF_ORDER   ((size_t)34950784)     //  1,600,000  int [E2P] pairs sorted by locality key
#define OFF_BASE2   ((size_t)36550784)     //    204,800  int [SCN] (pair-key CSR)
#define OFF_OFS2    ((size_t)36755584)     //    204,800  int [SCN] (counters)
#define OFF_PRC     ((size_t)36960384)     //  6,400,000  int4 [E2P] {sp,dp,pz0,pz1} sorted
#define OFF_WN      ((size_t)43360384)     //  3,200,000  float2 [E2P] {w,nrm} sorted
#define OFF_M       ((size_t)46560384)     // 12,800,000  f16 [E2P][16] packed m (in-place)
#define OFF_EIS     ((size_t)59360384)     //  3,200,000  int2 [E2P] {src,dst} sorted
#define WS_NEED     ((size_t)62560384)

// 2-D locality key: src-bucket (1024 nodes) major, dst-bucket (64 nodes) minor
__device__ __forceinline__ int key2(int s, int d) {
    return ((s >> 10) << 10) | (d >> 6);
}

// bijective XCD-aware block remap: each XCD gets a contiguous chunk
__device__ __forceinline__ int xcd_swz(int bid, int nwg) {
    int q = nwg >> 3, r = nwg & 7;
    int x = bid & 7, idx = bid >> 3;
    return (x < r ? x * (q + 1) : r * (q + 1) + (x - r) * q) + idx;
}

// ---------------- degree count + pair-key count (fused) ----------------
__global__ void k_deg(const int* __restrict__ ei, int* __restrict__ deg,
                      int* __restrict__ cnt2) {
    int e = blockIdx.x * 256 + threadIdx.x;   // grid exact: EDD
    int v = ei[e];
    atomicAdd(&deg[v], 1);
    if (e < E2P) {
        int d = ei[EDD + e];
        atomicAdd(&cnt2[key2(v, d)], 1);
    }
}

__global__ void k_node(const int* __restrict__ deg, float* __restrict__ logdeg,
                       float* __restrict__ degc) {
    int n = blockIdx.x * 256 + threadIdx.x;
    if (n < NN) {
        float d = (float)deg[n];
        logdeg[n] = logf(d + 1.0f);
        degc[n]   = fmaxf(d, 1.0f);
    }
}

// ---------------- SCN-sized prefix-sum (3 tiny kernels, grid = NBLK exact) ------------
__global__ void k_scan1(const int* __restrict__ deg, int* __restrict__ incl,
                        int* __restrict__ blk) {
    __shared__ int sm[256];
    int i = blockIdx.x * 256 + threadIdx.x;
    int v = deg[i];
    sm[threadIdx.x] = v;
    __syncthreads();
    for (int off = 1; off < 256; off <<= 1) {
        int t = (threadIdx.x >= off) ? sm[threadIdx.x - off] : 0;
        __syncthreads();
        sm[threadIdx.x] += t;
        __syncthreads();
    }
    incl[i] = sm[threadIdx.x];
    if (threadIdx.x == 255) blk[blockIdx.x] = sm[255];
}

__global__ void k_scan2(int* __restrict__ blk) {
    __shared__ int sm[256];
    int v = (threadIdx.x < NBLK) ? blk[threadIdx.x] : 0;
    sm[threadIdx.x] = v;
    __syncthreads();
    for (int off = 1; off < 256; off <<= 1) {
        int t = (threadIdx.x >= off) ? sm[threadIdx.x - off] : 0;
        __syncthreads();
        sm[threadIdx.x] += t;
        __syncthreads();
    }
    if (threadIdx.x < NBLK) blk[threadIdx.x] = sm[threadIdx.x];
}

__global__ void k_scan3(const int* __restrict__ incl, const int* __restrict__ deg,
                        const int* __restrict__ blk, int* __restrict__ base) {
    int i = blockIdx.x * 256 + threadIdx.x;
    int off = (blockIdx.x > 0) ? blk[blockIdx.x - 1] : 0;
    base[i] = off + incl[i] - deg[i];
}

// pos[e] = CSR slot of directed edge e within its dst node's segment
__global__ void k_pos(const int* __restrict__ ei, const int* __restrict__ base,
                      int* __restrict__ cnt, int* __restrict__ pos) {
    int e = blockIdx.x * 256 + threadIdx.x;   // grid exact: EDD
    int dstn = ei[EDD + e];
    pos[e] = base[dstn] + atomicAdd(&cnt[dstn], 1);
}

// locality sort fill: order + eiS written at the scatter destination (k_gath fused)
__global__ void k_order(const int* __restrict__ ei, const int* __restrict__ base2,
                        int* __restrict__ ofs2, int* __restrict__ order,
                        int2* __restrict__ eiS) {
    int p = blockIdx.x * 256 + threadIdx.x;
    if (p < E2P) {
        int s = ei[p], d = ei[EDD + p];
        int k = key2(s, d);
        int dst = base2[k] + atomicAdd(&ofs2[k], 1);
        order[dst] = p;
        eiS[dst] = make_int2(s, d);
    }
}

// ---------------- weight prep ----------------
// Bt K-order for h8 gathers: MFMA step tm (0..15), lane q, element e=2j+typ
//   k' = tm*32 + q*8 + 2j + typ  <->  column c = (tm>>1)*32 + q*8 + (tm&1)*4 + j
//   typ 0 = product feature (row c), typ 1 = absdiff (row 256+c). k'=512,513: struct.
__global__ void k_prep(const float* __restrict__ enc_w1, const float* __restrict__ edge_w1,
                       const float* __restrict__ R_raw, const float* __restrict__ Rsl,
                       const float* __restrict__ mlog,
                       _Float16* __restrict__ Wt, _Float16* __restrict__ Bt,
                       float* __restrict__ Rs) {
    int gid = blockIdx.x * 256 + threadIdx.x;
    if (gid < 256 * 512) {                       // Wt[n][k] = enc_w1[k][n]
        int n = gid >> 9, k = gid & 511;
        Wt[n * 512 + k] = (_Float16)enc_w1[k * 256 + n];
        return;
    }
    int g2 = gid - 256 * 512;
    if (g2 < 64 * 544) {                         // Bt[n][k'] with h8-gather K perm
        int n = g2 / 544, k = g2 - n * 544;
        float v = 0.0f;
        if (k < 512) {
            int tm = k >> 5, r = k & 31;
            int qq = r >> 3, jj = (r >> 1) & 3, typ = k & 1;
            int c = (tm >> 1) * 32 + qq * 8 + (tm & 1) * 4 + jj;
            v = edge_w1[(typ ? 256 + c : c) * 64 + n];
        } else if (k < 514) {
            v = edge_w1[k * 64 + n];
        }
        Bt[n * 544 + k] = (_Float16)v;
        return;
    }
    int g3 = g2 - 64 * 544;
    if (g3 < 64) {
        int c = g3 >> 3, d = g3 & 7;
        float rv = 0.5f * (R_raw[c * 8 + d] + R_raw[d * 8 + c]);
        float s  = log1pf(expf(Rsl[0])) + 1e-6f;
        Rs[g3] = s * tanhf(rv);
        return;
    }
    if (g3 == 64) {
        Rs[64] = 1.5f / (1.0f + expf(-mlog[0]));
    }
}

// ---------------- encoder layer 1: 64 rows/block, no X-LDS, W double-buffered --------
// (round-6/7 structure: 76 VGPR main loop, measured 79-80 us)
__global__ __launch_bounds__(256) void k_enc(const float* __restrict__ x,
                                             const _Float16* __restrict__ Wt,
                                             const float* __restrict__ b1,
                                             _Float16* __restrict__ hf) {
    __shared__ _Float16 WL[2][256 * 40];   // 2 x 20 KB
    const int tid = threadIdx.x;
    const int wid = tid >> 6;
    const int lane = tid & 63;
    const int l15 = lane & 15;
    const int q = lane >> 4;
    const int m0 = blockIdx.x * 64;
    const int row = m0 + wid * 16 + l15;
    const bool ract = (row < NN);
    const float* xrow = x + (size_t)row * IND;

    f4 acc[16];
#pragma unroll
    for (int i = 0; i < 16; i++) acc[i] = (f4){0.f, 0.f, 0.f, 0.f};

    const int wn = tid >> 2;          // staging: W row
    const int wo = (tid & 3) * 8;     // staging: col offset

    // preload kt=0
    h8 wreg[4];
#pragma unroll
    for (int rep = 0; rep < 4; rep++)
        wreg[rep] = *(const h8*)(Wt + (size_t)(rep * 64 + wn) * IND + wo);
    f4 xa = (f4){0, 0, 0, 0}, xb = (f4){0, 0, 0, 0};
    if (ract) {
        const f4* xp = (const f4*)(xrow + q * 8);
        xa = xp[0]; xb = xp[1];
    }

    for (int kt = 0; kt < 16; kt++) {
        const int cur = kt & 1;
#pragma unroll
        for (int rep = 0; rep < 4; rep++)
            *(h8*)&WL[cur][(rep * 64 + wn) * 40 + wo] = wreg[rep];
        __syncthreads();
        f4 xa2, xb2;
        if (kt < 15) {                  // prefetch kt+1 while MFMAs run
            const int kc = (kt + 1) * 32;
#pragma unroll
            for (int rep = 0; rep < 4; rep++)
                wreg[rep] = *(const h8*)(Wt + (size_t)(rep * 64 + wn) * IND + kc + wo);
            if (ract) {
                const f4* xp = (const f4*)(xrow + kc + q * 8);
                xa2 = xp[0]; xb2 = xp[1];
            }
        }
        h8 a;
#pragma unroll
        for (int u = 0; u < 4; u++) { a[u] = (_Float16)xa[u]; a[4 + u] = (_Float16)xb[u]; }
#pragma unroll
        for (int nt = 0; nt < 16; nt++) {
            h8 b = *(const h8*)&WL[cur][(nt * 16 + l15) * 40 + q * 8];
            acc[nt] = __builtin_amdgcn_mfma_f32_16x16x32_f16(a, b, acc[nt], 0, 0, 0);
        }
        if (kt < 15 && ract) { xa = xa2; xb = xb2; }
        __syncthreads();   // protect WL[cur] until all waves' MFMA reads done
    }
#pragma unroll
    for (int nt = 0; nt < 16; nt++) {
        int col = nt * 16 + l15;
        float bv = b1[col];
#pragma unroll
        for (int reg = 0; reg < 4; reg++) {
            int orow = m0 + wid * 16 + q * 4 + reg;
            if (orow < NN) {
                float v = acc[nt][reg] + bv;
                hf[(size_t)orow * HIDN + col] = (_Float16)fmaxf(v, 0.f);
            }
        }
    }
}

// ---------------- encoder layer 2 + log_softmax -> Z[n][0:8] ----------------
__global__ void k_logits(const _Float16* __restrict__ hf, const float* __restrict__ w2,
                         const float* __restrict__ b2, float* __restrict__ Z) {
    __shared__ float w2L[2048];
    for (int i = threadIdx.x; i < 2048; i += 256) w2L[i] = w2[i];
    __syncthreads();
    int n = blockIdx.x * 256 + threadIdx.x;
    if (n >= NN) return;
    float sum[8];
#pragma unroll
    for (int c = 0; c < 8; c++) sum[c] = b2[c];
    for (int kb = 0; kb < 32; kb++) {
        h8 hv = *(const h8*)(hf + (size_t)n * HIDN + kb * 8);
#pragma unroll
        for (int u = 0; u < 8; u++) {
            float hx = (float)hv[u];
            const float* wr = &w2L[(kb * 8 + u) * 8];
#pragma unroll
            for (int c = 0; c < 8; c++) sum[c] += hx * wr[c];
        }
    }
    float mx = sum[0];
#pragma unroll
    for (int c = 1; c < 8; c++) mx = fmaxf(mx, sum[c]);
    float se = 0.f;
#pragma unroll
    for (int c = 0; c < 8; c++) se += __expf(sum[c] - mx);
    float lse = __logf(se);
#pragma unroll
    for (int c = 0; c < 8; c++) Z[(size_t)n * 16 + c] = sum[c] - mx - lse;
}

// ---------------- edge MLP over locality-sorted pairs + XCD chunking -----------------
__global__ __launch_bounds__(256) void k_edge(const int2* __restrict__ eiS,
        const _Float16* __restrict__ hf, const float* __restrict__ logdeg,
        const _Float16* __restrict__ BtG, const float* __restrict__ eb1,
        const float* __restrict__ ew2, const float* __restrict__ eb2,
        float* __restrict__ wsym2) {
    __shared__ _Float16 BtL[64 * 136];
    const int tid = threadIdx.x;
    const int wid = tid >> 6;
    const int lane = tid & 63;
    const int l15 = lane & 15;
    const int q = lane >> 4;
    const int eb = xcd_swz(blockIdx.x, gridDim.x) * 128;  // grid exact: E2P/128 = 3125

    int sidx[2], didx[2];
    float la[2], lb[2];
#pragma unroll
    for (int mt = 0; mt < 2; mt++) {
        int e = eb + wid * 32 + mt * 16 + l15;   // always < E2P
        int2 sd = eiS[e];
        sidx[mt] = sd.x;
        didx[mt] = sd.y;
        la[mt] = logdeg[sidx[mt]];
        lb[mt] = logdeg[didx[mt]];
    }

    f4 acc[2][4];
#pragma unroll
    for (int a = 0; a < 2; a++)
#pragma unroll
        for (int b = 0; b < 4; b++) acc[a][b] = (f4){0.f, 0.f, 0.f, 0.f};

    const _Float16* hq = hf + q * 8;            // lane's 16B column slice
    h8 curS[2], curD[2];
#pragma unroll
    for (int mt = 0; mt < 2; mt++) {            // kk=0 fragments (cols q*8..q*8+7)
        curS[mt] = *(const h8*)(hq + (size_t)sidx[mt] * HIDN);
        curD[mt] = *(const h8*)(hq + (size_t)didx[mt] * HIDN);
    }

    for (int ph = 0; ph < 4; ph++) {
        __syncthreads();
        {   // stage 64 rows x 128 cols of Bt (r=tid>>2 mapping: conflict-free writes)
            const int r = tid >> 2;
            const int c0 = tid & 3;
            const int kbase = ph * 128;
#pragma unroll
            for (int i2 = 0; i2 < 4; i2++) {
                int ck = c0 + i2 * 4;
                *(h8*)&BtL[r * 136 + ck * 8] =
                    *(const h8*)(BtG + (size_t)r * 544 + kbase + ck * 8);
            }
        }
        __syncthreads();
#pragma unroll
        for (int kk2 = 0; kk2 < 2; kk2++) {
            const int kk = ph * 2 + kk2;
            h8 nxtS[2], nxtD[2];
            if (kk < 7) {                        // prefetch next 16B slice
                const int c1 = (kk + 1) * 32;
#pragma unroll
                for (int mt = 0; mt < 2; mt++) {
                    nxtS[mt] = *(const h8*)(hq + (size_t)sidx[mt] * HIDN + c1);
                    nxtD[mt] = *(const h8*)(hq + (size_t)didx[mt] * HIDN + c1);
                }
            }
            const int ko = kk2 * 64 + q * 8;
            // half 0 (cols +0..3)
            {
                h8 a0[2];
#pragma unroll
                for (int mt = 0; mt < 2; mt++) {
#pragma unroll
                    for (int j = 0; j < 4; j++) {
                        float x1 = (float)curS[mt][j], x2 = (float)curD[mt][j];
                        a0[mt][2 * j]     = (_Float16)(x1 * x2);
                        a0[mt][2 * j + 1] = (_Float16)fabsf(x1 - x2);
                    }
                }
                h8 bf[4];
#pragma unroll
                for (int nt = 0; nt < 4; nt++)
                    bf[nt] = *(const h8*)&BtL[(nt * 16 + l15) * 136 + ko];
#pragma unroll
                for (int mt = 0; mt < 2; mt++)
#pragma unroll
                    for (int nt = 0; nt < 4; nt++)
                        acc[mt][nt] = __builtin_amdgcn_mfma_f32_16x16x32_f16(a0[mt], bf[nt], acc[mt][nt], 0, 0, 0);
            }
            // half 1 (cols +4..7)
            {
                h8 a1[2];
#pragma unroll
                for (int mt = 0; mt < 2; mt++) {
#pragma unroll
                    for (int j = 0; j < 4; j++) {
                        float x1 = (float)curS[mt][4 + j], x2 = (float)curD[mt][4 + j];
                        a1[mt][2 * j]     = (_Float16)(x1 * x2);
                        a1[mt][2 * j + 1] = (_Float16)fabsf(x1 - x2);
                    }
                }
                h8 bf[4];
#pragma unroll
                for (int nt = 0; nt < 4; nt++)
                    bf[nt] = *(const h8*)&BtL[(nt * 16 + l15) * 136 + ko + 32];
#pragma unroll
                for (int mt = 0; mt < 2; mt++)
#pragma unroll
                    for (int nt = 0; nt < 4; nt++)
                        acc[mt][nt] = __builtin_amdgcn_mfma_f32_16x16x32_f16(a1[mt], bf[nt], acc[mt][nt], 0, 0, 0);
            }
            if (kk < 7) {
#pragma unroll
                for (int mt = 0; mt < 2; mt++) { curS[mt] = nxtS[mt]; curD[mt] = nxtD[mt]; }
            }
        }
    }

    // struct features step (k' = 512..543, only 512/513 nonzero)
    __syncthreads();
    {
        const int r = tid >> 2, ck = tid & 3;
        *(h8*)&BtL[r * 136 + ck * 8] = *(const h8*)(BtG + (size_t)r * 544 + 512 + ck * 8);
    }
    __syncthreads();
    {
        h8 bf[4];
#pragma unroll
        for (int nt = 0; nt < 4; nt++)
            bf[nt] = *(const h8*)&BtL[(nt * 16 + l15) * 136 + q * 8];
#pragma unroll
        for (int mt = 0; mt < 2; mt++) {
            h8 a = (h8){0, 0, 0, 0, 0, 0, 0, 0};
            if (q == 0) {
                a[0] = (_Float16)(la[mt] + lb[mt]);
                a[1] = (_Float16)fabsf(la[mt] - lb[mt]);
            }
#pragma unroll
            for (int nt = 0; nt < 4; nt++)
                acc[mt][nt] = __builtin_amdgcn_mfma_f32_16x16x32_f16(a, bf[nt], acc[mt][nt], 0, 0, 0);
        }
    }

    float b1v[4], w2v[4];
#pragma unroll
    for (int nt = 0; nt < 4; nt++) {
        int col = nt * 16 + l15;
        b1v[nt] = eb1[col];
        w2v[nt] = ew2[col];
    }
    const float b2s = eb2[0];
    float part[2][4];
#pragma unroll
    for (int mt = 0; mt < 2; mt++)
#pragma unroll
        for (int reg = 0; reg < 4; reg++) {
            float s = 0.f;
#pragma unroll
            for (int nt = 0; nt < 4; nt++) {
                float v = acc[mt][nt][reg] + b1v[nt];
                s += fmaxf(v, 0.f) * w2v[nt];
            }
            part[mt][reg] = s;
        }
#pragma unroll
    for (int off = 1; off < 16; off <<= 1)
#pragma unroll
        for (int mt = 0; mt < 2; mt++)
#pragma unroll
            for (int reg = 0; reg < 4; reg++)
                part[mt][reg] += __shfl_xor(part[mt][reg], off, 64);
    if (l15 == 0) {
#pragma unroll
        for (int mt = 0; mt < 2; mt++)
#pragma unroll
            for (int reg = 0; reg < 4; reg++) {
                int er = eb + wid * 32 + mt * 16 + q * 4 + reg;
                if (er < E2P) {
                    float xr = part[mt][reg] + b2s;
                    wsym2[er] = 0.8f / (1.0f + __expf(-xr));   // sorted index
                }
            }
    }
}

// ======== BP: locality-sorted pairs; packed state; kprod-recompute exclusion ========

// symmetric K-product: f = m @ exp(w*Rs), 36 unique exps (Rs symmetric)
__device__ __forceinline__ void kprod(const float* __restrict__ RsL, float w,
                                      const float* me, const float* mr,
                                      float* fe, float* fr) {
#pragma unroll
    for (int d = 0; d < 8; d++) { fe[d] = 0.f; fr[d] = 0.f; }
#pragma unroll
    for (int c = 0; c < 8; c++) {
        {
            float kv = __expf(w * RsL[c * 8 + c]);
            fe[c] += me[c] * kv;
            fr[c] += mr[c] * kv;
        }
#pragma unroll
        for (int d = c + 1; d < 8; d++) {
            float kv = __expf(w * RsL[c * 8 + d]);
            fe[d] += me[c] * kv; fr[d] += mr[c] * kv;
            fe[c] += me[d] * kv; fr[c] += mr[d] * kv;
        }
    }
}

// init (sorted index i): write packed state + m + logf
__global__ __launch_bounds__(256) void k_init(const int2* __restrict__ eiS,
        const float* __restrict__ wsym2, const float* __restrict__ degc,
        const float* __restrict__ Rs, const float* __restrict__ Z,
        const int* __restrict__ pos, const int* __restrict__ order,
        i4* __restrict__ prc, float2* __restrict__ wn,
        _Float16* __restrict__ M, _Float16* __restrict__ logf) {
    __shared__ float RsL[64];
    const int tid = threadIdx.x;
    if (tid < 64) RsL[tid] = Rs[tid];
    __syncthreads();
    int i = xcd_swz(blockIdx.x, EBLK) * 256 + tid;
    if (i >= E2P) return;
    int p = order[i];
    int2 sd = eiS[i];
    int sp = sd.x, dp = sd.y;
    float w = wsym2[i];
    float nrm = rsqrtf(degc[sp] * degc[dp]);
    int pz0 = pos[p], pz1 = pos[E2P + p];
    prc[i] = (i4){sp, dp, pz0, pz1};
    wn[i] = make_float2(w, nrm);
    const f4* Zs = (const f4*)(Z + (size_t)sp * 16);
    const f4* Zd = (const f4*)(Z + (size_t)dp * 16);
    f4 ls0 = Zs[0], ls1 = Zs[1], ld0 = Zd[0], ld1 = Zd[1];
    float lps[8], lpd[8];
#pragma unroll
    for (int u = 0; u < 4; u++) { lps[u] = ls0[u]; lps[4+u] = ls1[u]; lpd[u] = ld0[u]; lpd[4+u] = ld1[u]; }
    float me[8], mr[8];
    {
        float mx = lps[0], mx2 = lpd[0];
#pragma unroll
        for (int d = 1; d < 8; d++) { mx = fmaxf(mx, lps[d]); mx2 = fmaxf(mx2, lpd[d]); }
        float s = 0.f, s2 = 0.f;
#pragma unroll
        for (int d = 0; d < 8; d++) { me[d] = __expf(lps[d] - mx); s += me[d];
                                      mr[d] = __expf(lpd[d] - mx2); s2 += mr[d]; }
        float rs = 1.f / s, rs2 = 1.f / s2;
#pragma unroll
        for (int d = 0; d < 8; d++) { me[d] *= rs; mr[d] *= rs2; }
    }
    {
        h8 mh, mh2;
#pragma unroll
        for (int d = 0; d < 8; d++) { mh[d] = (_Float16)me[d]; mh2[d] = (_Float16)mr[d]; }
        *(h8*)(M + (size_t)i * 16)     = mh;
        *(h8*)(M + (size_t)i * 16 + 8) = mh2;
    }
    float fe[8], fr[8];
    kprod(RsL, w, me, mr, fe, fr);
    h8 le, lr;
#pragma unroll
    for (int d = 0; d < 8; d++) {
        le[d] = (_Float16)(__logf(fmaxf(fe[d], 1e-12f)) * nrm);
        lr[d] = (_Float16)(__logf(fmaxf(fr[d], 1e-12f)) * nrm);
    }
    *(h8*)(logf + (size_t)pz0 * 8) = le;   // -> dp's segment
    *(h8*)(logf + (size_t)pz1 * 8) = lr;   // -> sp's segment
}

// fused BP step (sorted index i): exclusion via kprod recompute (verified config)
__global__ __launch_bounds__(256) void k_bpF(const i4* __restrict__ prc,
        const float2* __restrict__ wn, const float* __restrict__ Rs,
        const float* __restrict__ Z, _Float16* __restrict__ M,
        _Float16* __restrict__ logf) {
    __shared__ float RsL[64];
    const int tid = threadIdx.x;
    if (tid < 64) RsL[tid] = Rs[tid];
    __syncthreads();
    int i = xcd_swz(blockIdx.x, EBLK) * 256 + tid;
    if (i >= E2P) return;
    i4 c4 = prc[i];
    const int sp = c4[0], dp = c4[1], pz0 = c4[2], pz1 = c4[3];
    float2 wnv = wn[i];
    const float w = wnv.x, nrm = wnv.y;
    const float alpha = Rs[64];
    h8 mhe = *(const h8*)(M + (size_t)i * 16);
    h8 mhr = *(const h8*)(M + (size_t)i * 16 + 8);
    float me[8], mr[8];
#pragma unroll
    for (int d = 0; d < 8; d++) { me[d] = (float)mhe[d]; mr[d] = (float)mhr[d]; }
    float fe[8], fr[8];
    kprod(RsL, w, me, mr, fe, fr);
    float lfe[8], lfr[8];
#pragma unroll
    for (int d = 0; d < 8; d++) {
        lfe[d] = __logf(fmaxf(fe[d], 1e-12f)) * nrm;
        lfr[d] = __logf(fmaxf(fr[d], 1e-12f)) * nrm;
    }
    const f4* Zs = (const f4*)(Z + (size_t)sp * 16);
    const f4* Zd = (const f4*)(Z + (size_t)dp * 16);
    f4 ls0 = Zs[0], ls1 = Zs[1], ss0 = Zs[2], ss1 = Zs[3];
    f4 ld0 = Zd[0], ld1 = Zd[1], sd0 = Zd[2], sd1 = Zd[3];
    float te[8], tr[8];
#pragma unroll
    for (int u = 0; u < 4; u++) {
        te[u]     = ls0[u] + alpha * (ss0[u] - lfr[u]);
        te[4 + u] = ls1[u] + alpha * (ss1[u] - lfr[4 + u]);
        tr[u]     = ld0[u] + alpha * (sd0[u] - lfe[u]);
        tr[4 + u] = ld1[u] + alpha * (sd1[u] - lfe[4 + u]);
    }
    float m1[8], m2[8];
    {
        float mx = te[0], mx2 = tr[0];
#pragma unroll
        for (int d = 1; d < 8; d++) { mx = fmaxf(mx, te[d]); mx2 = fmaxf(mx2, tr[d]); }
        float s = 0.f, s2 = 0.f;
#pragma unroll
        for (int d = 0; d < 8; d++) { m1[d] = __expf(te[d] - mx); s += m1[d];
                                      m2[d] = __expf(tr[d] - mx2); s2 += m2[d]; }
        float rs = 1.f / s, rs2 = 1.f / s2;
        float t1 = 0.f, t2 = 0.f;
#pragma unroll
        for (int d = 0; d < 8; d++) {
            m1[d] = fmaxf(0.8f * me[d] + 0.2f * m1[d] * rs, 1e-12f);  t1 += m1[d];
            m2[d] = fmaxf(0.8f * mr[d] + 0.2f * m2[d] * rs2, 1e-12f); t2 += m2[d];
        }
        float rt1 = 1.f / t1, rt2 = 1.f / t2;
#pragma unroll
        for (int d = 0; d < 8; d++) { m1[d] *= rt1; m2[d] *= rt2; }
    }
    {
        h8 mh, mh2;
#pragma unroll
        for (int d = 0; d < 8; d++) { mh[d] = (_Float16)m1[d]; mh2[d] = (_Float16)m2[d]; }
        *(h8*)(M + (size_t)i * 16)     = mh;
        *(h8*)(M + (size_t)i * 16 + 8) = mh2;
    }
    // new log_f for next iteration's sum
    float fe2[8], fr2[8];
    kprod(RsL, w, m1, m2, fe2, fr2);
    h8 le, lr;
#pragma unroll
    for (int d = 0; d < 8; d++) {
        le[d] = (_Float16)(__logf(fmaxf(fe2[d], 1e-12f)) * nrm);
        lr[d] = (_Float16)(__logf(fmaxf(fr2[d], 1e-12f)) * nrm);
    }
    *(h8*)(logf + (size_t)pz0 * 8) = le;
    *(h8*)(logf + (size_t)pz1 * 8) = lr;
}

// ---------------- sum_in: CSR reduction, h8 loads + 8-lane fold-reduce ----------------
// fin==0: write S to Z[n][8+j].  fin==1: beliefs = softmax(log_phi + alpha*S) -> out.
__global__ void k_sum(const _Float16* __restrict__ logf, const int* __restrict__ base,
                      const int* __restrict__ deg, float* __restrict__ Z,
                      const float* __restrict__ Rs, float* __restrict__ out, int fin) {
    int g = blockIdx.x * 256 + threadIdx.x;
    int n = g >> 3;
    if (n >= NN) return;
    int j = threadIdx.x & 7;
    int b = base[n], cnt = deg[n];
    float acc[8];
#pragma unroll
    for (int d = 0; d < 8; d++) acc[d] = 0.f;
    for (int s = j; s < cnt; s += 8) {
        h8 v = *(const h8*)(logf + (size_t)(b + s) * 8);
#pragma unroll
        for (int d = 0; d < 8; d++) acc[d] += (float)v[d];
    }
    int lane = threadIdx.x & 63;
    float v4[4], v2[2], r;
    {
        bool hi = (lane & 4) != 0;
#pragma unroll
        for (int i = 0; i < 4; i++) {
            float send = hi ? acc[i] : acc[i + 4];
            float recv = __shfl_xor(send, 4, 64);
            v4[i] = (hi ? acc[i + 4] : acc[i]) + recv;
        }
    }
    {
        bool hi = (lane & 2) != 0;
#pragma unroll
        for (int i = 0; i < 2; i++) {
            float send = hi ? v4[i] : v4[i + 2];
            float recv = __shfl_xor(send, 2, 64);
            v2[i] = (hi ? v4[i + 2] : v4[i]) + recv;
        }
    }
    {
        bool hi = (lane & 1) != 0;
        float send = hi ? v2[0] : v2[1];
        float recv = __shfl_xor(send, 1, 64);
        r = (hi ? v2[1] : v2[0]) + recv;
    }
    if (!fin) {
        Z[(size_t)n * 16 + 8 + j] = r;
    } else {
        float alpha = Rs[64];
        float v = Z[(size_t)n * 16 + j] + alpha * r;
        float mx = v;
        mx = fmaxf(mx, __shfl_xor(mx, 1, 64));
        mx = fmaxf(mx, __shfl_xor(mx, 2, 64));
        mx = fmaxf(mx, __shfl_xor(mx, 4, 64));
        float ex = __expf(v - mx);
        float s = ex;
        s += __shfl_xor(s, 1, 64); s += __shfl_xor(s, 2, 64); s += __shfl_xor(s, 4, 64);
        out[(size_t)n * 8 + j] = ex / s;
    }
}

extern "C" void kernel_launch(void* const* d_in, const int* in_sizes, int n_in,
                              void* d_out, int out_size, void* d_ws, size_t ws_size,
                              hipStream_t stream) {
    if (ws_size < WS_NEED) return;
    const float* x        = (const float*)d_in[0];
    const int*   ei       = (const int*)d_in[1];
    const float* enc_w1   = (const float*)d_in[3];
    const float* enc_b1   = (const float*)d_in[4];
    const float* enc_w2   = (const float*)d_in[5];
    const float* enc_b2   = (const float*)d_in[6];
    const float* edge_w1  = (const float*)d_in[7];
    const float* edge_b1  = (const float*)d_in[8];
    const float* edge_w2  = (const float*)d_in[9];
    const float* edge_b2  = (const float*)d_in[10];
    const float* R_raw    = (const float*)d_in[11];
    const float* Rsl      = (const float*)d_in[12];
    const float* mlog     = (const float*)d_in[13];

    char* ws = (char*)d_ws;
    _Float16* hf     = (_Float16*)(ws + OFF_HF16);
    _Float16* logfb  = (_Float16*)(ws + OFF_LOGF);
    float* Zb        = (float*)(ws + OFF_Z);
    int*   deg       = (int*)  (ws + OFF_DEG);
    float* logdeg    = (float*)(ws + OFF_LOGDEG);
    float* degc      = (float*)(ws + OFF_DEGC);
    int*   baseA     = (int*)  (ws + OFF_BASE);
    int*   cnt       = (int*)  (ws + OFF_CNT);
    int*   blk       = (int*)  (ws + OFF_BLK);
    _Float16* Wt     = (_Float16*)(ws + OFF_WT);
    _Float16* Bt     = (_Float16*)(ws + OFF_BT);
    float* Rs        = (float*)(ws + OFF_RS);
    float* wsym2     = (float*)(ws + OFF_WSYM);
    int*   pos       = (int*)  (ws + OFF_POS);
    int*   order     = (int*)  (ws + OFF_ORDER);
    int*   base2     = (int*)  (ws + OFF_BASE2);
    int*   ofs2      = (int*)  (ws + OFF_OFS2);
    i4*    prc       = (i4*)   (ws + OFF_PRC);
    float2* wnb      = (float2*)(ws + OFF_WN);
    _Float16* Mb     = (_Float16*)(ws + OFF_M);
    int2*  eiS       = (int2*) (ws + OFF_EIS);
    float* outp      = (float*)d_out;

    hipMemsetAsync(deg, 0, (size_t)SCN * 4, stream);
    hipMemsetAsync(ofs2, 0, (size_t)SCN * 4, stream);
    k_deg<<<dim3(EDD / 256), dim3(256), 0, stream>>>(ei, deg, ofs2);
    k_node<<<dim3(NBLK), dim3(256), 0, stream>>>(deg, logdeg, degc);
    k_prep<<<dim3((256 * 512 + 64 * 544 + 65 + 255) / 256), dim3(256), 0, stream>>>(
        enc_w1, edge_w1, R_raw, Rsl, mlog, Wt, Bt, Rs);
    // dst-CSR build (one-time)
    k_scan1<<<dim3(NBLK), dim3(256), 0, stream>>>(deg, cnt /*incl scratch*/, blk);
    k_scan2<<<dim3(1), dim3(256), 0, stream>>>(blk);
    k_scan3<<<dim3(NBLK), dim3(256), 0, stream>>>(cnt, deg, blk, baseA);
    hipMemsetAsync(cnt, 0, (size_t)SCN * 4, stream);
    k_pos<<<dim3(EDD / 256), dim3(256), 0, stream>>>(ei, baseA, cnt, pos);
    // pair locality sort (one-time): key = (src>>10)*1024 | (dst>>6)
    k_scan1<<<dim3(NBLK), dim3(256), 0, stream>>>(ofs2, cnt, blk);
    k_scan2<<<dim3(1), dim3(256), 0, stream>>>(blk);
    k_scan3<<<dim3(NBLK), dim3(256), 0, stream>>>(cnt, ofs2, blk, base2);
    hipMemsetAsync(ofs2, 0, (size_t)SCN * 4, stream);
    k_order<<<dim3(EBLK), dim3(256), 0, stream>>>(ei, base2, ofs2, order, eiS);
    // encoder + edge MLP
    k_enc<<<dim3((NN + 63) / 64), dim3(256), 0, stream>>>(x, Wt, enc_b1, hf);
    k_logits<<<dim3(NBLK), dim3(256), 0, stream>>>(hf, enc_w2, enc_b2, Zb);
    k_edge<<<dim3(E2P / 128), dim3(256), 0, stream>>>(eiS, hf, logdeg, Bt, edge_b1,
                                                      edge_w2, edge_b2, wsym2);
    // BP loop (logfb aliases hf — hf is dead from here on)
    k_init<<<dim3(EBLK), dim3(256), 0, stream>>>(eiS, wsym2, degc, Rs, Zb, pos, order,
                                                 prc, wnb, Mb, logfb);
    k_sum<<<dim3((NN * 8 + 255) / 256), dim3(256), 0, stream>>>(logfb, baseA, deg, Zb,
                                                                Rs, outp, 0);
    for (int t = 0; t < 10; t++) {
        k_bpF<<<dim3(EBLK), dim3(256), 0, stream>>>(prc, wnb, Rs, Zb, Mb, logfb);
        k_sum<<<dim3((NN * 8 + 255) / 256), dim3(256), 0, stream>>>(logfb, baseA, deg, Zb,
                                                                    Rs, outp, (t == 9) ? 1 : 0);
    }
    (void)in_sizes; (void)n_in; (void)out_size;
}

// Round 11
// 793.535 us; speedup vs baseline: 1.0532x; 1.0046x over previous
//
#include <hip/hip_runtime.h>
#include <cstddef>
#include <cstdint>

typedef _Float16 h4 __attribute__((ext_vector_type(4)));
typedef _Float16 h8 __attribute__((ext_vector_type(8)));
typedef float    f4 __attribute__((ext_vector_type(4)));
typedef int      i4 __attribute__((ext_vector_type(4)));

#define NN      50000
#define IND     512
#define HIDN    256
#define E2P     400000
#define EDD     800000
#define NBLK    196    // scan blocks
#define SCN     50176  // NBLK*256: scan domain (>= NN+1 and >= key space)
#define EBLK    1563   // ceil(E2P/256)

// ---- workspace layout (bytes) ----
// logf (f16 [EDD][8] = 12.8MB) aliases hf (dead after k_edge)
#define OFF_HF16    ((size_t)0)            // 25,600,000  f16 h [NN][256]
#define OFF_LOGF    ((size_t)0)            // 12,800,000  f16 [EDD][8] (CSR order)
#define OFF_Z       ((size_t)25600000)     //  3,200,000  f32 [NN][16]: [0:8]=log_phi, [8:16]=S
#define OFF_DEG     ((size_t)28800000)     //    204,800  int [SCN]
#define OFF_LOGDEG  ((size_t)29004800)     //    200,000  f32
#define OFF_DEGC    ((size_t)29204800)     //    200,000  f32
#define OFF_BASE    ((size_t)29404800)     //    204,800  int [SCN] (dst-CSR scan)
#define OFF_CNT     ((size_t)29609600)     //    204,800  int [SCN] (scan scratch / counters)
#define OFF_BLK     ((size_t)29814400)     //      4,096  int (dual scan block sums: A@0, B@512)
#define OFF_WT      ((size_t)29818496)     //    262,144  f16 enc_w1^T
#define OFF_BT      ((size_t)30080640)     //     69,632  f16 edge_w1 perm^T (h8-gather K-order)
#define OFF_RS      ((size_t)30150272)     //        512  f32 Rs[64] + alpha at [64]
#define OFF_WSYM    ((size_t)30150784)     //  1,600,000  f32 [E2P] wsym2 (SORTED pair order)
#define OFF_POS     ((size_t)31750784)     //  3,200,000  int [EDD]; first SCN ints double as inclB scratch
#define OFF_ORDER   ((size_t)34950784)     //  1,600,000  int [E2P] pairs sorted by locality key
#define OFF_BASE2   ((size_t)36550784)     //    204,800  int [SCN] (pair-key CSR)
#define OFF_OFS2    ((size_t)36755584)     //    204,800  int [SCN] (counters)
#define OFF_PRC     ((size_t)36960384)     //  6,400,000  int4 [E2P] {sp,dp,pz0,pz1} sorted
#define OFF_WN      ((size_t)43360384)     //  3,200,000  float2 [E2P] {w,nrm} sorted
#define OFF_M       ((size_t)46560384)     // 12,800,000  f16 [E2P][16] packed m (in-place)
#define OFF_EIS     ((size_t)59360384)     //  3,200,000  int2 [E2P] {src,dst} sorted
#define WS_NEED     ((size_t)62560384)

// 2-D locality key: src-bucket (1024 nodes) major, dst-bucket (64 nodes) minor
__device__ __forceinline__ int key2(int s, int d) {
    return ((s >> 10) << 10) | (d >> 6);
}

// bijective XCD-aware block remap: each XCD gets a contiguous chunk
__device__ __forceinline__ int xcd_swz(int bid, int nwg) {
    int q = nwg >> 3, r = nwg & 7;
    int x = bid & 7, idx = bid >> 3;
    return (x < r ? x * (q + 1) : r * (q + 1) + (x - r) * q) + idx;
}

// ---------------- degree count + pair-key count (fused) ----------------
__global__ void k_deg(const int* __restrict__ ei, int* __restrict__ deg,
                      int* __restrict__ cnt2) {
    int e = blockIdx.x * 256 + threadIdx.x;   // grid exact: EDD
    int v = ei[e];
    atomicAdd(&deg[v], 1);
    if (e < E2P) {
        int d = ei[EDD + e];
        atomicAdd(&cnt2[key2(v, d)], 1);
    }
}

// ---------------- dual prefix-sum pipeline (3 kernels) + fused node-values ------------
// scanA: block-inclusive scans of deg AND cnt2; also emits logdeg/degc (k_node fused)
__global__ void k_scanA(const int* __restrict__ deg, const int* __restrict__ cnt2,
                        int* __restrict__ inclA, int* __restrict__ inclB,
                        int* __restrict__ blk, float* __restrict__ logdeg,
                        float* __restrict__ degc) {
    __shared__ int smA[256], smB[256];
    int i = blockIdx.x * 256 + threadIdx.x;
    int vA = deg[i], vB = cnt2[i];
    if (i < NN) {
        float d = (float)vA;
        logdeg[i] = logf(d + 1.0f);
        degc[i]   = fmaxf(d, 1.0f);
    }
    smA[threadIdx.x] = vA; smB[threadIdx.x] = vB;
    __syncthreads();
    for (int off = 1; off < 256; off <<= 1) {
        int tA = (threadIdx.x >= off) ? smA[threadIdx.x - off] : 0;
        int tB = (threadIdx.x >= off) ? smB[threadIdx.x - off] : 0;
        __syncthreads();
        smA[threadIdx.x] += tA; smB[threadIdx.x] += tB;
        __syncthreads();
    }
    inclA[i] = smA[threadIdx.x];
    inclB[i] = smB[threadIdx.x];
    if (threadIdx.x == 255) {
        blk[blockIdx.x]       = smA[255];
        blk[512 + blockIdx.x] = smB[255];
    }
}

__global__ void k_scanB(int* __restrict__ blk) {
    __shared__ int smA[256], smB[256];
    int vA = (threadIdx.x < NBLK) ? blk[threadIdx.x] : 0;
    int vB = (threadIdx.x < NBLK) ? blk[512 + threadIdx.x] : 0;
    smA[threadIdx.x] = vA; smB[threadIdx.x] = vB;
    __syncthreads();
    for (int off = 1; off < 256; off <<= 1) {
        int tA = (threadIdx.x >= off) ? smA[threadIdx.x - off] : 0;
        int tB = (threadIdx.x >= off) ? smB[threadIdx.x - off] : 0;
        __syncthreads();
        smA[threadIdx.x] += tA; smB[threadIdx.x] += tB;
        __syncthreads();
    }
    if (threadIdx.x < NBLK) {
        blk[threadIdx.x]       = smA[threadIdx.x];
        blk[512 + threadIdx.x] = smB[threadIdx.x];
    }
}

// scanC: exclusive bases for both pipelines; zeroes the counter arrays in-place
__global__ void k_scanC(int* __restrict__ inclA /*cnt*/, const int* __restrict__ deg,
                        const int* __restrict__ inclB, int* __restrict__ cnt2 /*ofs2*/,
                        const int* __restrict__ blk,
                        int* __restrict__ baseA, int* __restrict__ base2) {
    int i = blockIdx.x * 256 + threadIdx.x;
    int offA = (blockIdx.x > 0) ? blk[blockIdx.x - 1] : 0;
    int offB = (blockIdx.x > 0) ? blk[512 + blockIdx.x - 1] : 0;
    baseA[i] = offA + inclA[i] - deg[i];
    base2[i] = offB + inclB[i] - cnt2[i];
    inclA[i] = 0;   // cnt  -> k_posord dst counters
    cnt2[i]  = 0;   // ofs2 -> k_posord key counters
}

// fused: pos[e] (dst-CSR slot) + locality-sort fill (order, eiS)
__global__ void k_posord(const int* __restrict__ ei, const int* __restrict__ baseA,
                         int* __restrict__ cnt, const int* __restrict__ base2,
                         int* __restrict__ ofs2, int* __restrict__ pos,
                         int* __restrict__ order, int2* __restrict__ eiS) {
    int e = blockIdx.x * 256 + threadIdx.x;   // grid exact: EDD
    int dstn = ei[EDD + e];
    pos[e] = baseA[dstn] + atomicAdd(&cnt[dstn], 1);
    if (e < E2P) {
        int s = ei[e];
        int k = key2(s, dstn);
        int dst = base2[k] + atomicAdd(&ofs2[k], 1);
        order[dst] = e;
        eiS[dst] = make_int2(s, dstn);
    }
}

// ---------------- weight prep ----------------
// Bt K-order for h8 gathers: MFMA step tm (0..15), lane q, element e=2j+typ
//   k' = tm*32 + q*8 + 2j + typ  <->  column c = (tm>>1)*32 + q*8 + (tm&1)*4 + j
//   typ 0 = product feature (row c), typ 1 = absdiff (row 256+c). k'=512,513: struct.
__global__ void k_prep(const float* __restrict__ enc_w1, const float* __restrict__ edge_w1,
                       const float* __restrict__ R_raw, const float* __restrict__ Rsl,
                       const float* __restrict__ mlog,
                       _Float16* __restrict__ Wt, _Float16* __restrict__ Bt,
                       float* __restrict__ Rs) {
    int gid = blockIdx.x * 256 + threadIdx.x;
    if (gid < 256 * 512) {                       // Wt[n][k] = enc_w1[k][n]
        int n = gid >> 9, k = gid & 511;
        Wt[n * 512 + k] = (_Float16)enc_w1[k * 256 + n];
        return;
    }
    int g2 = gid - 256 * 512;
    if (g2 < 64 * 544) {                         // Bt[n][k'] with h8-gather K perm
        int n = g2 / 544, k = g2 - n * 544;
        float v = 0.0f;
        if (k < 512) {
            int tm = k >> 5, r = k & 31;
            int qq = r >> 3, jj = (r >> 1) & 3, typ = k & 1;
            int c = (tm >> 1) * 32 + qq * 8 + (tm & 1) * 4 + jj;
            v = edge_w1[(typ ? 256 + c : c) * 64 + n];
        } else if (k < 514) {
            v = edge_w1[k * 64 + n];
        }
        Bt[n * 544 + k] = (_Float16)v;
        return;
    }
    int g3 = g2 - 64 * 544;
    if (g3 < 64) {
        int c = g3 >> 3, d = g3 & 7;
        float rv = 0.5f * (R_raw[c * 8 + d] + R_raw[d * 8 + c]);
        float s  = log1pf(expf(Rsl[0])) + 1e-6f;
        Rs[g3] = s * tanhf(rv);
        return;
    }
    if (g3 == 64) {
        Rs[64] = 1.5f / (1.0f + expf(-mlog[0]));
    }
}

// ---------------- encoder layer 1: 64 rows/block, no X-LDS, W double-buffered --------
// (round-6/7 structure: 76 VGPR main loop, measured 79-80 us)
__global__ __launch_bounds__(256) void k_enc(const float* __restrict__ x,
                                             const _Float16* __restrict__ Wt,
                                             const float* __restrict__ b1,
                                             _Float16* __restrict__ hf) {
    __shared__ _Float16 WL[2][256 * 40];   // 2 x 20 KB
    const int tid = threadIdx.x;
    const int wid = tid >> 6;
    const int lane = tid & 63;
    const int l15 = lane & 15;
    const int q = lane >> 4;
    const int m0 = blockIdx.x * 64;
    const int row = m0 + wid * 16 + l15;
    const bool ract = (row < NN);
    const float* xrow = x + (size_t)row * IND;

    f4 acc[16];
#pragma unroll
    for (int i = 0; i < 16; i++) acc[i] = (f4){0.f, 0.f, 0.f, 0.f};

    const int wn = tid >> 2;          // staging: W row
    const int wo = (tid & 3) * 8;     // staging: col offset

    // preload kt=0
    h8 wreg[4];
#pragma unroll
    for (int rep = 0; rep < 4; rep++)
        wreg[rep] = *(const h8*)(Wt + (size_t)(rep * 64 + wn) * IND + wo);
    f4 xa = (f4){0, 0, 0, 0}, xb = (f4){0, 0, 0, 0};
    if (ract) {
        const f4* xp = (const f4*)(xrow + q * 8);
        xa = xp[0]; xb = xp[1];
    }

    for (int kt = 0; kt < 16; kt++) {
        const int cur = kt & 1;
#pragma unroll
        for (int rep = 0; rep < 4; rep++)
            *(h8*)&WL[cur][(rep * 64 + wn) * 40 + wo] = wreg[rep];
        __syncthreads();
        f4 xa2, xb2;
        if (kt < 15) {                  // prefetch kt+1 while MFMAs run
            const int kc = (kt + 1) * 32;
#pragma unroll
            for (int rep = 0; rep < 4; rep++)
                wreg[rep] = *(const h8*)(Wt + (size_t)(rep * 64 + wn) * IND + kc + wo);
            if (ract) {
                const f4* xp = (const f4*)(xrow + kc + q * 8);
                xa2 = xp[0]; xb2 = xp[1];
            }
        }
        h8 a;
#pragma unroll
        for (int u = 0; u < 4; u++) { a[u] = (_Float16)xa[u]; a[4 + u] = (_Float16)xb[u]; }
#pragma unroll
        for (int nt = 0; nt < 16; nt++) {
            h8 b = *(const h8*)&WL[cur][(nt * 16 + l15) * 40 + q * 8];
            acc[nt] = __builtin_amdgcn_mfma_f32_16x16x32_f16(a, b, acc[nt], 0, 0, 0);
        }
        if (kt < 15 && ract) { xa = xa2; xb = xb2; }
        __syncthreads();   // protect WL[cur] until all waves' MFMA reads done
    }
#pragma unroll
    for (int nt = 0; nt < 16; nt++) {
        int col = nt * 16 + l15;
        float bv = b1[col];
#pragma unroll
        for (int reg = 0; reg < 4; reg++) {
            int orow = m0 + wid * 16 + q * 4 + reg;
            if (orow < NN) {
                float v = acc[nt][reg] + bv;
                hf[(size_t)orow * HIDN + col] = (_Float16)fmaxf(v, 0.f);
            }
        }
    }
}

// ---------------- encoder layer 2 + log_softmax -> Z[n][0:8] ----------------
__global__ void k_logits(const _Float16* __restrict__ hf, const float* __restrict__ w2,
                         const float* __restrict__ b2, float* __restrict__ Z) {
    __shared__ float w2L[2048];
    for (int i = threadIdx.x; i < 2048; i += 256) w2L[i] = w2[i];
    __syncthreads();
    int n = blockIdx.x * 256 + threadIdx.x;
    if (n >= NN) return;
    float sum[8];
#pragma unroll
    for (int c = 0; c < 8; c++) sum[c] = b2[c];
    for (int kb = 0; kb < 32; kb++) {
        h8 hv = *(const h8*)(hf + (size_t)n * HIDN + kb * 8);
#pragma unroll
        for (int u = 0; u < 8; u++) {
            float hx = (float)hv[u];
            const float* wr = &w2L[(kb * 8 + u) * 8];
#pragma unroll
            for (int c = 0; c < 8; c++) sum[c] += hx * wr[c];
        }
    }
    float mx = sum[0];
#pragma unroll
    for (int c = 1; c < 8; c++) mx = fmaxf(mx, sum[c]);
    float se = 0.f;
#pragma unroll
    for (int c = 0; c < 8; c++) se += __expf(sum[c] - mx);
    float lse = __logf(se);
#pragma unroll
    for (int c = 0; c < 8; c++) Z[(size_t)n * 16 + c] = sum[c] - mx - lse;
}

// ---------------- edge MLP over locality-sorted pairs + XCD chunking -----------------
__global__ __launch_bounds__(256) void k_edge(const int2* __restrict__ eiS,
        const _Float16* __restrict__ hf, const float* __restrict__ logdeg,
        const _Float16* __restrict__ BtG, const float* __restrict__ eb1,
        const float* __restrict__ ew2, const float* __restrict__ eb2,
        float* __restrict__ wsym2) {
    __shared__ _Float16 BtL[64 * 136];
    const int tid = threadIdx.x;
    const int wid = tid >> 6;
    const int lane = tid & 63;
    const int l15 = lane & 15;
    const int q = lane >> 4;
    const int eb = xcd_swz(blockIdx.x, gridDim.x) * 128;  // grid exact: E2P/128 = 3125

    int sidx[2], didx[2];
    float la[2], lb[2];
#pragma unroll
    for (int mt = 0; mt < 2; mt++) {
        int e = eb + wid * 32 + mt * 16 + l15;   // always < E2P
        int2 sd = eiS[e];
        sidx[mt] = sd.x;
        didx[mt] = sd.y;
        la[mt] = logdeg[sidx[mt]];
        lb[mt] = logdeg[didx[mt]];
    }

    f4 acc[2][4];
#pragma unroll
    for (int a = 0; a < 2; a++)
#pragma unroll
        for (int b = 0; b < 4; b++) acc[a][b] = (f4){0.f, 0.f, 0.f, 0.f};

    const _Float16* hq = hf + q * 8;            // lane's 16B column slice
    h8 curS[2], curD[2];
#pragma unroll
    for (int mt = 0; mt < 2; mt++) {            // kk=0 fragments (cols q*8..q*8+7)
        curS[mt] = *(const h8*)(hq + (size_t)sidx[mt] * HIDN);
        curD[mt] = *(const h8*)(hq + (size_t)didx[mt] * HIDN);
    }

    for (int ph = 0; ph < 4; ph++) {
        __syncthreads();
        {   // stage 64 rows x 128 cols of Bt (r=tid>>2 mapping: conflict-free writes)
            const int r = tid >> 2;
            const int c0 = tid & 3;
            const int kbase = ph * 128;
#pragma unroll
            for (int i2 = 0; i2 < 4; i2++) {
                int ck = c0 + i2 * 4;
                *(h8*)&BtL[r * 136 + ck * 8] =
                    *(const h8*)(BtG + (size_t)r * 544 + kbase + ck * 8);
            }
        }
        __syncthreads();
#pragma unroll
        for (int kk2 = 0; kk2 < 2; kk2++) {
            const int kk = ph * 2 + kk2;
            h8 nxtS[2], nxtD[2];
            if (kk < 7) {                        // prefetch next 16B slice
                const int c1 = (kk + 1) * 32;
#pragma unroll
                for (int mt = 0; mt < 2; mt++) {
                    nxtS[mt] = *(const h8*)(hq + (size_t)sidx[mt] * HIDN + c1);
                    nxtD[mt] = *(const h8*)(hq + (size_t)didx[mt] * HIDN + c1);
                }
            }
            const int ko = kk2 * 64 + q * 8;
            // half 0 (cols +0..3)
            {
                h8 a0[2];
#pragma unroll
                for (int mt = 0; mt < 2; mt++) {
#pragma unroll
                    for (int j = 0; j < 4; j++) {
                        float x1 = (float)curS[mt][j], x2 = (float)curD[mt][j];
                        a0[mt][2 * j]     = (_Float16)(x1 * x2);
                        a0[mt][2 * j + 1] = (_Float16)fabsf(x1 - x2);
                    }
                }
                h8 bf[4];
#pragma unroll
                for (int nt = 0; nt < 4; nt++)
                    bf[nt] = *(const h8*)&BtL[(nt * 16 + l15) * 136 + ko];
#pragma unroll
                for (int mt = 0; mt < 2; mt++)
#pragma unroll
                    for (int nt = 0; nt < 4; nt++)
                        acc[mt][nt] = __builtin_amdgcn_mfma_f32_16x16x32_f16(a0[mt], bf[nt], acc[mt][nt], 0, 0, 0);
            }
            // half 1 (cols +4..7)
            {
                h8 a1[2];
#pragma unroll
                for (int mt = 0; mt < 2; mt++) {
#pragma unroll
                    for (int j = 0; j < 4; j++) {
                        float x1 = (float)curS[mt][4 + j], x2 = (float)curD[mt][4 + j];
                        a1[mt][2 * j]     = (_Float16)(x1 * x2);
                        a1[mt][2 * j + 1] = (_Float16)fabsf(x1 - x2);
                    }
                }
                h8 bf[4];
#pragma unroll
                for (int nt = 0; nt < 4; nt++)
                    bf[nt] = *(const h8*)&BtL[(nt * 16 + l15) * 136 + ko + 32];
#pragma unroll
                for (int mt = 0; mt < 2; mt++)
#pragma unroll
                    for (int nt = 0; nt < 4; nt++)
                        acc[mt][nt] = __builtin_amdgcn_mfma_f32_16x16x32_f16(a1[mt], bf[nt], acc[mt][nt], 0, 0, 0);
            }
            if (kk < 7) {
#pragma unroll
                for (int mt = 0; mt < 2; mt++) { curS[mt] = nxtS[mt]; curD[mt] = nxtD[mt]; }
            }
        }
    }

    // struct features step (k' = 512..543, only 512/513 nonzero)
    __syncthreads();
    {
        const int r = tid >> 2, ck = tid & 3;
        *(h8*)&BtL[r * 136 + ck * 8] = *(const h8*)(BtG + (size_t)r * 544 + 512 + ck * 8);
    }
    __syncthreads();
    {
        h8 bf[4];
#pragma unroll
        for (int nt = 0; nt < 4; nt++)
            bf[nt] = *(const h8*)&BtL[(nt * 16 + l15) * 136 + q * 8];
#pragma unroll
        for (int mt = 0; mt < 2; mt++) {
            h8 a = (h8){0, 0, 0, 0, 0, 0, 0, 0};
            if (q == 0) {
                a[0] = (_Float16)(la[mt] + lb[mt]);
                a[1] = (_Float16)fabsf(la[mt] - lb[mt]);
            }
#pragma unroll
            for (int nt = 0; nt < 4; nt++)
                acc[mt][nt] = __builtin_amdgcn_mfma_f32_16x16x32_f16(a, bf[nt], acc[mt][nt], 0, 0, 0);
        }
    }

    float b1v[4], w2v[4];
#pragma unroll
    for (int nt = 0; nt < 4; nt++) {
        int col = nt * 16 + l15;
        b1v[nt] = eb1[col];
        w2v[nt] = ew2[col];
    }
    const float b2s = eb2[0];
    float part[2][4];
#pragma unroll
    for (int mt = 0; mt < 2; mt++)
#pragma unroll
        for (int reg = 0; reg < 4; reg++) {
            float s = 0.f;
#pragma unroll
            for (int nt = 0; nt < 4; nt++) {
                float v = acc[mt][nt][reg] + b1v[nt];
                s += fmaxf(v, 0.f) * w2v[nt];
            }
            part[mt][reg] = s;
        }
#pragma unroll
    for (int off = 1; off < 16; off <<= 1)
#pragma unroll
        for (int mt = 0; mt < 2; mt++)
#pragma unroll
            for (int reg = 0; reg < 4; reg++)
                part[mt][reg] += __shfl_xor(part[mt][reg], off, 64);
    if (l15 == 0) {
#pragma unroll
        for (int mt = 0; mt < 2; mt++)
#pragma unroll
            for (int reg = 0; reg < 4; reg++) {
                int er = eb + wid * 32 + mt * 16 + q * 4 + reg;
                if (er < E2P) {
                    float xr = part[mt][reg] + b2s;
                    wsym2[er] = 0.8f / (1.0f + __expf(-xr));   // sorted index
                }
            }
    }
}

// ======== BP: locality-sorted pairs; packed state; kprod-recompute exclusion ========

// symmetric K-product: f = m @ exp(w*Rs), 36 unique exps (Rs symmetric)
__device__ __forceinline__ void kprod(const float* __restrict__ RsL, float w,
                                      const float* me, const float* mr,
                                      float* fe, float* fr) {
#pragma unroll
    for (int d = 0; d < 8; d++) { fe[d] = 0.f; fr[d] = 0.f; }
#pragma unroll
    for (int c = 0; c < 8; c++) {
        {
            float kv = __expf(w * RsL[c * 8 + c]);
            fe[c] += me[c] * kv;
            fr[c] += mr[c] * kv;
        }
#pragma unroll
        for (int d = c + 1; d < 8; d++) {
            float kv = __expf(w * RsL[c * 8 + d]);
            fe[d] += me[c] * kv; fr[d] += mr[c] * kv;
            fe[c] += me[d] * kv; fr[c] += mr[d] * kv;
        }
    }
}

// init (sorted index i): write packed state + m + logf
__global__ __launch_bounds__(256) void k_init(const int2* __restrict__ eiS,
        const float* __restrict__ wsym2, const float* __restrict__ degc,
        const float* __restrict__ Rs, const float* __restrict__ Z,
        const int* __restrict__ pos, const int* __restrict__ order,
        i4* __restrict__ prc, float2* __restrict__ wn,
        _Float16* __restrict__ M, _Float16* __restrict__ logf) {
    __shared__ float RsL[64];
    const int tid = threadIdx.x;
    if (tid < 64) RsL[tid] = Rs[tid];
    __syncthreads();
    int i = xcd_swz(blockIdx.x, EBLK) * 256 + tid;
    if (i >= E2P) return;
    int p = order[i];
    int2 sd = eiS[i];
    int sp = sd.x, dp = sd.y;
    float w = wsym2[i];
    float nrm = rsqrtf(degc[sp] * degc[dp]);
    int pz0 = pos[p], pz1 = pos[E2P + p];
    prc[i] = (i4){sp, dp, pz0, pz1};
    wn[i] = make_float2(w, nrm);
    const f4* Zs = (const f4*)(Z + (size_t)sp * 16);
    const f4* Zd = (const f4*)(Z + (size_t)dp * 16);
    f4 ls0 = Zs[0], ls1 = Zs[1], ld0 = Zd[0], ld1 = Zd[1];
    float lps[8], lpd[8];
#pragma unroll
    for (int u = 0; u < 4; u++) { lps[u] = ls0[u]; lps[4+u] = ls1[u]; lpd[u] = ld0[u]; lpd[4+u] = ld1[u]; }
    float me[8], mr[8];
    {
        float mx = lps[0], mx2 = lpd[0];
#pragma unroll
        for (int d = 1; d < 8; d++) { mx = fmaxf(mx, lps[d]); mx2 = fmaxf(mx2, lpd[d]); }
        float s = 0.f, s2 = 0.f;
#pragma unroll
        for (int d = 0; d < 8; d++) { me[d] = __expf(lps[d] - mx); s += me[d];
                                      mr[d] = __expf(lpd[d] - mx2); s2 += mr[d]; }
        float rs = 1.f / s, rs2 = 1.f / s2;
#pragma unroll
        for (int d = 0; d < 8; d++) { me[d] *= rs; mr[d] *= rs2; }
    }
    {
        h8 mh, mh2;
#pragma unroll
        for (int d = 0; d < 8; d++) { mh[d] = (_Float16)me[d]; mh2[d] = (_Float16)mr[d]; }
        *(h8*)(M + (size_t)i * 16)     = mh;
        *(h8*)(M + (size_t)i * 16 + 8) = mh2;
    }
    float fe[8], fr[8];
    kprod(RsL, w, me, mr, fe, fr);
    h8 le, lr;
#pragma unroll
    for (int d = 0; d < 8; d++) {
        le[d] = (_Float16)(__logf(fmaxf(fe[d], 1e-12f)) * nrm);
        lr[d] = (_Float16)(__logf(fmaxf(fr[d], 1e-12f)) * nrm);
    }
    *(h8*)(logf + (size_t)pz0 * 8) = le;   // -> dp's segment
    *(h8*)(logf + (size_t)pz1 * 8) = lr;   // -> sp's segment
}

// fused BP step (sorted index i): exclusion via kprod recompute (verified config)
__global__ __launch_bounds__(256) void k_bpF(const i4* __restrict__ prc,
        const float2* __restrict__ wn, const float* __restrict__ Rs,
        const float* __restrict__ Z, _Float16* __restrict__ M,
        _Float16* __restrict__ logf) {
    __shared__ float RsL[64];
    const int tid = threadIdx.x;
    if (tid < 64) RsL[tid] = Rs[tid];
    __syncthreads();
    int i = xcd_swz(blockIdx.x, EBLK) * 256 + tid;
    if (i >= E2P) return;
    i4 c4 = prc[i];
    const int sp = c4[0], dp = c4[1], pz0 = c4[2], pz1 = c4[3];
    float2 wnv = wn[i];
    const float w = wnv.x, nrm = wnv.y;
    const float alpha = Rs[64];
    h8 mhe = *(const h8*)(M + (size_t)i * 16);
    h8 mhr = *(const h8*)(M + (size_t)i * 16 + 8);
    float me[8], mr[8];
#pragma unroll
    for (int d = 0; d < 8; d++) { me[d] = (float)mhe[d]; mr[d] = (float)mhr[d]; }
    float fe[8], fr[8];
    kprod(RsL, w, me, mr, fe, fr);
    float lfe[8], lfr[8];
#pragma unroll
    for (int d = 0; d < 8; d++) {
        lfe[d] = __logf(fmaxf(fe[d], 1e-12f)) * nrm;
        lfr[d] = __logf(fmaxf(fr[d], 1e-12f)) * nrm;
    }
    const f4* Zs = (const f4*)(Z + (size_t)sp * 16);
    const f4* Zd = (const f4*)(Z + (size_t)dp * 16);
    f4 ls0 = Zs[0], ls1 = Zs[1], ss0 = Zs[2], ss1 = Zs[3];
    f4 ld0 = Zd[0], ld1 = Zd[1], sd0 = Zd[2], sd1 = Zd[3];
    float te[8], tr[8];
#pragma unroll
    for (int u = 0; u < 4; u++) {
        te[u]     = ls0[u] + alpha * (ss0[u] - lfr[u]);
        te[4 + u] = ls1[u] + alpha * (ss1[u] - lfr[4 + u]);
        tr[u]     = ld0[u] + alpha * (sd0[u] - lfe[u]);
        tr[4 + u] = ld1[u] + alpha * (sd1[u] - lfe[4 + u]);
    }
    float m1[8], m2[8];
    {
        float mx = te[0], mx2 = tr[0];
#pragma unroll
        for (int d = 1; d < 8; d++) { mx = fmaxf(mx, te[d]); mx2 = fmaxf(mx2, tr[d]); }
        float s = 0.f, s2 = 0.f;
#pragma unroll
        for (int d = 0; d < 8; d++) { m1[d] = __expf(te[d] - mx); s += m1[d];
                                      m2[d] = __expf(tr[d] - mx2); s2 += m2[d]; }
        float rs = 1.f / s, rs2 = 1.f / s2;
        float t1 = 0.f, t2 = 0.f;
#pragma unroll
        for (int d = 0; d < 8; d++) {
            m1[d] = fmaxf(0.8f * me[d] + 0.2f * m1[d] * rs, 1e-12f);  t1 += m1[d];
            m2[d] = fmaxf(0.8f * mr[d] + 0.2f * m2[d] * rs2, 1e-12f); t2 += m2[d];
        }
        float rt1 = 1.f / t1, rt2 = 1.f / t2;
#pragma unroll
        for (int d = 0; d < 8; d++) { m1[d] *= rt1; m2[d] *= rt2; }
    }
    {
        h8 mh, mh2;
#pragma unroll
        for (int d = 0; d < 8; d++) { mh[d] = (_Float16)m1[d]; mh2[d] = (_Float16)m2[d]; }
        *(h8*)(M + (size_t)i * 16)     = mh;
        *(h8*)(M + (size_t)i * 16 + 8) = mh2;
    }
    // new log_f for next iteration's sum
    float fe2[8], fr2[8];
    kprod(RsL, w, m1, m2, fe2, fr2);
    h8 le, lr;
#pragma unroll
    for (int d = 0; d < 8; d++) {
        le[d] = (_Float16)(__logf(fmaxf(fe2[d], 1e-12f)) * nrm);
        lr[d] = (_Float16)(__logf(fmaxf(fr2[d], 1e-12f)) * nrm);
    }
    *(h8*)(logf + (size_t)pz0 * 8) = le;
    *(h8*)(logf + (size_t)pz1 * 8) = lr;
}

// ---------------- sum_in: CSR reduction, h8 loads + 8-lane fold-reduce ----------------
// cnt derived from base[n+1]-base[n] (base SCN-sized; deg[i]=0 for i>=NN).
// fin==0: write S to Z[n][8+j].  fin==1: beliefs = softmax(log_phi + alpha*S) -> out.
__global__ void k_sum(const _Float16* __restrict__ logf, const int* __restrict__ base,
                      float* __restrict__ Z, const float* __restrict__ Rs,
                      float* __restrict__ out, int fin) {
    int g = blockIdx.x * 256 + threadIdx.x;
    int n = g >> 3;
    if (n >= NN) return;
    int j = threadIdx.x & 7;
    int b = base[n], cnt = base[n + 1] - b;
    float acc[8];
#pragma unroll
    for (int d = 0; d < 8; d++) acc[d] = 0.f;
    for (int s = j; s < cnt; s += 8) {
        h8 v = *(const h8*)(logf + (size_t)(b + s) * 8);
#pragma unroll
        for (int d = 0; d < 8; d++) acc[d] += (float)v[d];
    }
    int lane = threadIdx.x & 63;
    float v4[4], v2[2], r;
    {
        bool hi = (lane & 4) != 0;
#pragma unroll
        for (int i = 0; i < 4; i++) {
            float send = hi ? acc[i] : acc[i + 4];
            float recv = __shfl_xor(send, 4, 64);
            v4[i] = (hi ? acc[i + 4] : acc[i]) + recv;
        }
    }
    {
        bool hi = (lane & 2) != 0;
#pragma unroll
        for (int i = 0; i < 2; i++) {
            float send = hi ? v4[i] : v4[i + 2];
            float recv = __shfl_xor(send, 2, 64);
            v2[i] = (hi ? v4[i + 2] : v4[i]) + recv;
        }
    }
    {
        bool hi = (lane & 1) != 0;
        float send = hi ? v2[0] : v2[1];
        float recv = __shfl_xor(send, 1, 64);
        r = (hi ? v2[1] : v2[0]) + recv;
    }
    if (!fin) {
        Z[(size_t)n * 16 + 8 + j] = r;
    } else {
        float alpha = Rs[64];
        float v = Z[(size_t)n * 16 + j] + alpha * r;
        float mx = v;
        mx = fmaxf(mx, __shfl_xor(mx, 1, 64));
        mx = fmaxf(mx, __shfl_xor(mx, 2, 64));
        mx = fmaxf(mx, __shfl_xor(mx, 4, 64));
        float ex = __expf(v - mx);
        float s = ex;
        s += __shfl_xor(s, 1, 64); s += __shfl_xor(s, 2, 64); s += __shfl_xor(s, 4, 64);
        out[(size_t)n * 8 + j] = ex / s;
    }
}

extern "C" void kernel_launch(void* const* d_in, const int* in_sizes, int n_in,
                              void* d_out, int out_size, void* d_ws, size_t ws_size,
                              hipStream_t stream) {
    if (ws_size < WS_NEED) return;
    const float* x        = (const float*)d_in[0];
    const int*   ei       = (const int*)d_in[1];
    const float* enc_w1   = (const float*)d_in[3];
    const float* enc_b1   = (const float*)d_in[4];
    const float* enc_w2   = (const float*)d_in[5];
    const float* enc_b2   = (const float*)d_in[6];
    const float* edge_w1  = (const float*)d_in[7];
    const float* edge_b1  = (const float*)d_in[8];
    const float* edge_w2  = (const float*)d_in[9];
    const float* edge_b2  = (const float*)d_in[10];
    const float* R_raw    = (const float*)d_in[11];
    const float* Rsl      = (const float*)d_in[12];
    const float* mlog     = (const float*)d_in[13];

    char* ws = (char*)d_ws;
    _Float16* hf     = (_Float16*)(ws + OFF_HF16);
    _Float16* logfb  = (_Float16*)(ws + OFF_LOGF);
    float* Zb        = (float*)(ws + OFF_Z);
    int*   deg       = (int*)  (ws + OFF_DEG);
    float* logdeg    = (float*)(ws + OFF_LOGDEG);
    float* degc      = (float*)(ws + OFF_DEGC);
    int*   baseA     = (int*)  (ws + OFF_BASE);
    int*   cnt       = (int*)  (ws + OFF_CNT);
    int*   blk       = (int*)  (ws + OFF_BLK);
    _Float16* Wt     = (_Float16*)(ws + OFF_WT);
    _Float16* Bt     = (_Float16*)(ws + OFF_BT);
    float* Rs        = (float*)(ws + OFF_RS);
    float* wsym2     = (float*)(ws + OFF_WSYM);
    int*   pos       = (int*)  (ws + OFF_POS);   // first SCN ints double as inclB scratch
    int*   order     = (int*)  (ws + OFF_ORDER);
    int*   base2     = (int*)  (ws + OFF_BASE2);
    int*   ofs2      = (int*)  (ws + OFF_OFS2);
    i4*    prc       = (i4*)   (ws + OFF_PRC);
    float2* wnb      = (float2*)(ws + OFF_WN);
    _Float16* Mb     = (_Float16*)(ws + OFF_M);
    int2*  eiS       = (int2*) (ws + OFF_EIS);
    float* outp      = (float*)d_out;

    hipMemsetAsync(deg, 0, (size_t)SCN * 4, stream);
    hipMemsetAsync(ofs2, 0, (size_t)SCN * 4, stream);
    k_deg<<<dim3(EDD / 256), dim3(256), 0, stream>>>(ei, deg, ofs2);
    k_prep<<<dim3((256 * 512 + 64 * 544 + 65 + 255) / 256), dim3(256), 0, stream>>>(
        enc_w1, edge_w1, R_raw, Rsl, mlog, Wt, Bt, Rs);
    // dual CSR build (one-time): dst-CSR + pair-locality-key CSR in one pipeline
    k_scanA<<<dim3(NBLK), dim3(256), 0, stream>>>(deg, ofs2, cnt, pos /*inclB scratch*/,
                                                  blk, logdeg, degc);
    k_scanB<<<dim3(1), dim3(256), 0, stream>>>(blk);
    k_scanC<<<dim3(NBLK), dim3(256), 0, stream>>>(cnt, deg, pos, ofs2, blk, baseA, base2);
    k_posord<<<dim3(EDD / 256), dim3(256), 0, stream>>>(ei, baseA, cnt, base2, ofs2,
                                                        pos, order, eiS);
    // encoder + edge MLP
    k_enc<<<dim3((NN + 63) / 64), dim3(256), 0, stream>>>(x, Wt, enc_b1, hf);
    k_logits<<<dim3(NBLK), dim3(256), 0, stream>>>(hf, enc_w2, enc_b2, Zb);
    k_edge<<<dim3(E2P / 128), dim3(256), 0, stream>>>(eiS, hf, logdeg, Bt, edge_b1,
                                                      edge_w2, edge_b2, wsym2);
    // BP loop (logfb aliases hf — hf is dead from here on)
    k_init<<<dim3(EBLK), dim3(256), 0, stream>>>(eiS, wsym2, degc, Rs, Zb, pos, order,
                                                 prc, wnb, Mb, logfb);
    k_sum<<<dim3((NN * 8 + 255) / 256), dim3(256), 0, stream>>>(logfb, baseA, Zb,
                                                                Rs, outp, 0);
    for (int t = 0; t < 10; t++) {
        k_bpF<<<dim3(EBLK), dim3(256), 0, stream>>>(prc, wnb, Rs, Zb, Mb, logfb);
        k_sum<<<dim3((NN * 8 + 255) / 256), dim3(256), 0, stream>>>(logfb, baseA, Zb,
                                                                    Rs, outp, (t == 9) ? 1 : 0);
    }
    (void)in_sizes; (void)n_in; (void)out_size;
}

// Round 12
// 730.970 us; speedup vs baseline: 1.1433x; 1.0856x over previous
//
#include <hip/hip_runtime.h>
#include <cstddef>
#include <cstdint>

typedef _Float16 h4 __attribute__((ext_vector_type(4)));
typedef _Float16 h8 __attribute__((ext_vector_type(8)));
typedef float    f4 __attribute__((ext_vector_type(4)));
typedef int      i4 __attribute__((ext_vector_type(4)));

#define NN      50000
#define IND     512
#define HIDN    256
#define E2P     400000
#define EDD     800000
#define NBLK    196    // scan blocks
#define SCN     50176  // NBLK*256: scan domain (>= NN+1 and >= key space)
#define EBLK    1563   // ceil(E2P/256)

// ---- workspace layout (bytes) ----
// logf (f16 [EDD][8] = 12.8MB) aliases hf (dead after k_edge)
#define OFF_HF16    ((size_t)0)            // 25,600,000  f16 h [NN][256]
#define OFF_LOGF    ((size_t)0)            // 12,800,000  f16 [EDD][8] (CSR order)
#define OFF_Z       ((size_t)25600000)     //  3,200,000  f32 [NN][16]: [0:8]=log_phi, [8:16]=S
#define OFF_DEG     ((size_t)28800000)     //    204,800  int [SCN] (inclA scan scratch)
#define OFF_LOGDEG  ((size_t)29004800)     //    200,000  f32
#define OFF_DEGC    ((size_t)29204800)     //    200,000  f32
#define OFF_BASE    ((size_t)29404800)     //    204,800  int [SCN] (dst-CSR bases)
#define OFF_CNT     ((size_t)29609600)     //    204,800  int [SCN] (dst counters; holds deg after k_rank)
#define OFF_BLK     ((size_t)29814400)     //      4,096  int (dual scan block sums: A@0, B@512)
#define OFF_WT      ((size_t)29818496)     //    262,144  f16 enc_w1^T
#define OFF_BT      ((size_t)30080640)     //     69,632  f16 edge_w1 perm^T (h8-gather K-order)
#define OFF_RS      ((size_t)30150272)     //        512  f32 Rs[64] + alpha at [64]
#define OFF_WSYM    ((size_t)30150784)     //  1,600,000  f32 [E2P] wsym2 (SORTED pair order)
#define OFF_POS     ((size_t)31750784)     //  3,200,000  int [EDD]; rank after k_rank, slot after k_fill
#define OFF_ORDER   ((size_t)34950784)     //  1,600,000  int [E2P] pairs sorted by locality key
#define OFF_BASE2   ((size_t)36550784)     //    204,800  int [SCN] (pair-key CSR bases)
#define OFF_OFS2    ((size_t)36755584)     //    204,800  int [SCN] (key counters; counts after k_rank)
#define OFF_PRC     ((size_t)36960384)     //  6,400,000  int4 [E2P] {sp,dp,pz0,pz1}; head doubles as inclB scratch
#define OFF_WN      ((size_t)43360384)     //  3,200,000  float2 [E2P] {w,nrm} sorted
#define OFF_M       ((size_t)46560384)     // 12,800,000  f16 [E2P][16] packed m (in-place)
#define OFF_EIS     ((size_t)59360384)     //  3,200,000  int2 [E2P] {src,dst} sorted
#define OFF_RK2     ((size_t)62560384)     //  1,600,000  int [E2P] pair key-rank
#define WS_NEED     ((size_t)64160384)

// 2-D locality key: src-bucket (1024 nodes) major, dst-bucket (64 nodes) minor
__device__ __forceinline__ int key2(int s, int d) {
    return ((s >> 10) << 10) | (d >> 6);
}

// bijective XCD-aware block remap: each XCD gets a contiguous chunk
__device__ __forceinline__ int xcd_swz(int bid, int nwg) {
    int q = nwg >> 3, r = nwg & 7;
    int x = bid & 7, idx = bid >> 3;
    return (x < r ? x * (q + 1) : r * (q + 1) + (x - r) * q) + idx;
}

// ---------------- rank assignment: the atomic returns ARE the counts ----------------
// pos[e] <- rank of e within its dst node (coalesced store); rk2[p] <- rank within key.
// After this kernel: cnt[] = deg counts, ofs2[] = key counts. No separate count pass.
__global__ void k_rank(const int* __restrict__ ei, int* __restrict__ cnt,
                       int* __restrict__ ofs2, int* __restrict__ pos,
                       int* __restrict__ rk2) {
    int e = blockIdx.x * 256 + threadIdx.x;   // grid exact: EDD
    int dstn = ei[EDD + e];
    pos[e] = atomicAdd(&cnt[dstn], 1);
    if (e < E2P) {
        int s = ei[e];
        rk2[e] = atomicAdd(&ofs2[key2(s, dstn)], 1);
    }
}

// ---------------- dual prefix-sum pipeline (3 kernels) + fused node-values ------------
// scanA: block-inclusive scans of cnt(deg) AND ofs2(key counts); emits logdeg/degc
__global__ void k_scanA(const int* __restrict__ cntIn, const int* __restrict__ cnt2In,
                        int* __restrict__ inclA, int* __restrict__ inclB,
                        int* __restrict__ blk, float* __restrict__ logdeg,
                        float* __restrict__ degc) {
    __shared__ int smA[256], smB[256];
    int i = blockIdx.x * 256 + threadIdx.x;
    int vA = cntIn[i], vB = cnt2In[i];
    if (i < NN) {
        float d = (float)vA;
        logdeg[i] = logf(d + 1.0f);
        degc[i]   = fmaxf(d, 1.0f);
    }
    smA[threadIdx.x] = vA; smB[threadIdx.x] = vB;
    __syncthreads();
    for (int off = 1; off < 256; off <<= 1) {
        int tA = (threadIdx.x >= off) ? smA[threadIdx.x - off] : 0;
        int tB = (threadIdx.x >= off) ? smB[threadIdx.x - off] : 0;
        __syncthreads();
        smA[threadIdx.x] += tA; smB[threadIdx.x] += tB;
        __syncthreads();
    }
    inclA[i] = smA[threadIdx.x];
    inclB[i] = smB[threadIdx.x];
    if (threadIdx.x == 255) {
        blk[blockIdx.x]       = smA[255];
        blk[512 + blockIdx.x] = smB[255];
    }
}

__global__ void k_scanB(int* __restrict__ blk) {
    __shared__ int smA[256], smB[256];
    int vA = (threadIdx.x < NBLK) ? blk[threadIdx.x] : 0;
    int vB = (threadIdx.x < NBLK) ? blk[512 + threadIdx.x] : 0;
    smA[threadIdx.x] = vA; smB[threadIdx.x] = vB;
    __syncthreads();
    for (int off = 1; off < 256; off <<= 1) {
        int tA = (threadIdx.x >= off) ? smA[threadIdx.x - off] : 0;
        int tB = (threadIdx.x >= off) ? smB[threadIdx.x - off] : 0;
        __syncthreads();
        smA[threadIdx.x] += tA; smB[threadIdx.x] += tB;
        __syncthreads();
    }
    if (threadIdx.x < NBLK) {
        blk[threadIdx.x]       = smA[threadIdx.x];
        blk[512 + threadIdx.x] = smB[threadIdx.x];
    }
}

// scanC: exclusive bases for both pipelines (counters stay intact; no zeroing needed)
__global__ void k_scanC(const int* __restrict__ inclA, const int* __restrict__ cntIn,
                        const int* __restrict__ inclB, const int* __restrict__ cnt2In,
                        const int* __restrict__ blk,
                        int* __restrict__ baseA, int* __restrict__ base2) {
    int i = blockIdx.x * 256 + threadIdx.x;
    int offA = (blockIdx.x > 0) ? blk[blockIdx.x - 1] : 0;
    int offB = (blockIdx.x > 0) ? blk[512 + blockIdx.x - 1] : 0;
    baseA[i] = offA + inclA[i] - cntIn[i];
    base2[i] = offB + inclB[i] - cnt2In[i];
}

// fill: pure loads/stores, NO atomics. pos[e] += baseA[dst]; scatter order/eiS.
__global__ void k_fill(const int* __restrict__ ei, const int* __restrict__ baseA,
                       const int* __restrict__ base2, const int* __restrict__ rk2,
                       int* __restrict__ pos, int* __restrict__ order,
                       int2* __restrict__ eiS) {
    int e = blockIdx.x * 256 + threadIdx.x;   // grid exact: EDD
    int dstn = ei[EDD + e];
    pos[e] += baseA[dstn];
    if (e < E2P) {
        int s = ei[e];
        int dst = base2[key2(s, dstn)] + rk2[e];
        order[dst] = e;
        eiS[dst] = make_int2(s, dstn);
    }
}

// ---------------- weight prep ----------------
// Bt K-order for h8 gathers: MFMA step tm (0..15), lane q, element e=2j+typ
//   k' = tm*32 + q*8 + 2j + typ  <->  column c = (tm>>1)*32 + q*8 + (tm&1)*4 + j
//   typ 0 = product feature (row c), typ 1 = absdiff (row 256+c). k'=512,513: struct.
__global__ void k_prep(const float* __restrict__ enc_w1, const float* __restrict__ edge_w1,
                       const float* __restrict__ R_raw, const float* __restrict__ Rsl,
                       const float* __restrict__ mlog,
                       _Float16* __restrict__ Wt, _Float16* __restrict__ Bt,
                       float* __restrict__ Rs) {
    int gid = blockIdx.x * 256 + threadIdx.x;
    if (gid < 256 * 512) {                       // Wt[n][k] = enc_w1[k][n]
        int n = gid >> 9, k = gid & 511;
        Wt[n * 512 + k] = (_Float16)enc_w1[k * 256 + n];
        return;
    }
    int g2 = gid - 256 * 512;
    if (g2 < 64 * 544) {                         // Bt[n][k'] with h8-gather K perm
        int n = g2 / 544, k = g2 - n * 544;
        float v = 0.0f;
        if (k < 512) {
            int tm = k >> 5, r = k & 31;
            int qq = r >> 3, jj = (r >> 1) & 3, typ = k & 1;
            int c = (tm >> 1) * 32 + qq * 8 + (tm & 1) * 4 + jj;
            v = edge_w1[(typ ? 256 + c : c) * 64 + n];
        } else if (k < 514) {
            v = edge_w1[k * 64 + n];
        }
        Bt[n * 544 + k] = (_Float16)v;
        return;
    }
    int g3 = g2 - 64 * 544;
    if (g3 < 64) {
        int c = g3 >> 3, d = g3 & 7;
        float rv = 0.5f * (R_raw[c * 8 + d] + R_raw[d * 8 + c]);
        float s  = log1pf(expf(Rsl[0])) + 1e-6f;
        Rs[g3] = s * tanhf(rv);
        return;
    }
    if (g3 == 64) {
        Rs[64] = 1.5f / (1.0f + expf(-mlog[0]));
    }
}

// ---------------- encoder layer 1: 64 rows/block, no X-LDS, W double-buffered --------
// (round-6/7 structure: 76 VGPR main loop, measured 79-80 us)
__global__ __launch_bounds__(256) void k_enc(const float* __restrict__ x,
                                             const _Float16* __restrict__ Wt,
                                             const float* __restrict__ b1,
                                             _Float16* __restrict__ hf) {
    __shared__ _Float16 WL[2][256 * 40];   // 2 x 20 KB
    const int tid = threadIdx.x;
    const int wid = tid >> 6;
    const int lane = tid & 63;
    const int l15 = lane & 15;
    const int q = lane >> 4;
    const int m0 = blockIdx.x * 64;
    const int row = m0 + wid * 16 + l15;
    const bool ract = (row < NN);
    const float* xrow = x + (size_t)row * IND;

    f4 acc[16];
#pragma unroll
    for (int i = 0; i < 16; i++) acc[i] = (f4){0.f, 0.f, 0.f, 0.f};

    const int wn = tid >> 2;          // staging: W row
    const int wo = (tid & 3) * 8;     // staging: col offset

    // preload kt=0
    h8 wreg[4];
#pragma unroll
    for (int rep = 0; rep < 4; rep++)
        wreg[rep] = *(const h8*)(Wt + (size_t)(rep * 64 + wn) * IND + wo);
    f4 xa = (f4){0, 0, 0, 0}, xb = (f4){0, 0, 0, 0};
    if (ract) {
        const f4* xp = (const f4*)(xrow + q * 8);
        xa = xp[0]; xb = xp[1];
    }

    for (int kt = 0; kt < 16; kt++) {
        const int cur = kt & 1;
#pragma unroll
        for (int rep = 0; rep < 4; rep++)
            *(h8*)&WL[cur][(rep * 64 + wn) * 40 + wo] = wreg[rep];
        __syncthreads();
        f4 xa2, xb2;
        if (kt < 15) {                  // prefetch kt+1 while MFMAs run
            const int kc = (kt + 1) * 32;
#pragma unroll
            for (int rep = 0; rep < 4; rep++)
                wreg[rep] = *(const h8*)(Wt + (size_t)(rep * 64 + wn) * IND + kc + wo);
            if (ract) {
                const f4* xp = (const f4*)(xrow + kc + q * 8);
                xa2 = xp[0]; xb2 = xp[1];
            }
        }
        h8 a;
#pragma unroll
        for (int u = 0; u < 4; u++) { a[u] = (_Float16)xa[u]; a[4 + u] = (_Float16)xb[u]; }
#pragma unroll
        for (int nt = 0; nt < 16; nt++) {
            h8 b = *(const h8*)&WL[cur][(nt * 16 + l15) * 40 + q * 8];
            acc[nt] = __builtin_amdgcn_mfma_f32_16x16x32_f16(a, b, acc[nt], 0, 0, 0);
        }
        if (kt < 15 && ract) { xa = xa2; xb = xb2; }
        __syncthreads();   // protect WL[cur] until all waves' MFMA reads done
    }
#pragma unroll
    for (int nt = 0; nt < 16; nt++) {
        int col = nt * 16 + l15;
        float bv = b1[col];
#pragma unroll
        for (int reg = 0; reg < 4; reg++) {
            int orow = m0 + wid * 16 + q * 4 + reg;
            if (orow < NN) {
                float v = acc[nt][reg] + bv;
                hf[(size_t)orow * HIDN + col] = (_Float16)fmaxf(v, 0.f);
            }
        }
    }
}

// ---------------- encoder layer 2 + log_softmax -> Z[n][0:8] ----------------
__global__ void k_logits(const _Float16* __restrict__ hf, const float* __restrict__ w2,
                         const float* __restrict__ b2, float* __restrict__ Z) {
    __shared__ float w2L[2048];
    for (int i = threadIdx.x; i < 2048; i += 256) w2L[i] = w2[i];
    __syncthreads();
    int n = blockIdx.x * 256 + threadIdx.x;
    if (n >= NN) return;
    float sum[8];
#pragma unroll
    for (int c = 0; c < 8; c++) sum[c] = b2[c];
    for (int kb = 0; kb < 32; kb++) {
        h8 hv = *(const h8*)(hf + (size_t)n * HIDN + kb * 8);
#pragma unroll
        for (int u = 0; u < 8; u++) {
            float hx = (float)hv[u];
            const float* wr = &w2L[(kb * 8 + u) * 8];
#pragma unroll
            for (int c = 0; c < 8; c++) sum[c] += hx * wr[c];
        }
    }
    float mx = sum[0];
#pragma unroll
    for (int c = 1; c < 8; c++) mx = fmaxf(mx, sum[c]);
    float se = 0.f;
#pragma unroll
    for (int c = 0; c < 8; c++) se += __expf(sum[c] - mx);
    float lse = __logf(se);
#pragma unroll
    for (int c = 0; c < 8; c++) Z[(size_t)n * 16 + c] = sum[c] - mx - lse;
}

// ---------------- edge MLP over locality-sorted pairs + XCD chunking -----------------
__global__ __launch_bounds__(256) void k_edge(const int2* __restrict__ eiS,
        const _Float16* __restrict__ hf, const float* __restrict__ logdeg,
        const _Float16* __restrict__ BtG, const float* __restrict__ eb1,
        const float* __restrict__ ew2, const float* __restrict__ eb2,
        float* __restrict__ wsym2) {
    __shared__ _Float16 BtL[64 * 136];
    const int tid = threadIdx.x;
    const int wid = tid >> 6;
    const int lane = tid & 63;
    const int l15 = lane & 15;
    const int q = lane >> 4;
    const int eb = xcd_swz(blockIdx.x, gridDim.x) * 128;  // grid exact: E2P/128 = 3125

    int sidx[2], didx[2];
    float la[2], lb[2];
#pragma unroll
    for (int mt = 0; mt < 2; mt++) {
        int e = eb + wid * 32 + mt * 16 + l15;   // always < E2P
        int2 sd = eiS[e];
        sidx[mt] = sd.x;
        didx[mt] = sd.y;
        la[mt] = logdeg[sidx[mt]];
        lb[mt] = logdeg[didx[mt]];
    }

    f4 acc[2][4];
#pragma unroll
    for (int a = 0; a < 2; a++)
#pragma unroll
        for (int b = 0; b < 4; b++) acc[a][b] = (f4){0.f, 0.f, 0.f, 0.f};

    const _Float16* hq = hf + q * 8;            // lane's 16B column slice
    h8 curS[2], curD[2];
#pragma unroll
    for (int mt = 0; mt < 2; mt++) {            // kk=0 fragments (cols q*8..q*8+7)
        curS[mt] = *(const h8*)(hq + (size_t)sidx[mt] * HIDN);
        curD[mt] = *(const h8*)(hq + (size_t)didx[mt] * HIDN);
    }

    for (int ph = 0; ph < 4; ph++) {
        __syncthreads();
        {   // stage 64 rows x 128 cols of Bt (r=tid>>2 mapping: conflict-free writes)
            const int r = tid >> 2;
            const int c0 = tid & 3;
            const int kbase = ph * 128;
#pragma unroll
            for (int i2 = 0; i2 < 4; i2++) {
                int ck = c0 + i2 * 4;
                *(h8*)&BtL[r * 136 + ck * 8] =
                    *(const h8*)(BtG + (size_t)r * 544 + kbase + ck * 8);
            }
        }
        __syncthreads();
#pragma unroll
        for (int kk2 = 0; kk2 < 2; kk2++) {
            const int kk = ph * 2 + kk2;
            h8 nxtS[2], nxtD[2];
            if (kk < 7) {                        // prefetch next 16B slice
                const int c1 = (kk + 1) * 32;
#pragma unroll
                for (int mt = 0; mt < 2; mt++) {
                    nxtS[mt] = *(const h8*)(hq + (size_t)sidx[mt] * HIDN + c1);
                    nxtD[mt] = *(const h8*)(hq + (size_t)didx[mt] * HIDN + c1);
                }
            }
            const int ko = kk2 * 64 + q * 8;
            // half 0 (cols +0..3)
            {
                h8 a0[2];
#pragma unroll
                for (int mt = 0; mt < 2; mt++) {
#pragma unroll
                    for (int j = 0; j < 4; j++) {
                        float x1 = (float)curS[mt][j], x2 = (float)curD[mt][j];
                        a0[mt][2 * j]     = (_Float16)(x1 * x2);
                        a0[mt][2 * j + 1] = (_Float16)fabsf(x1 - x2);
                    }
                }
                h8 bf[4];
#pragma unroll
                for (int nt = 0; nt < 4; nt++)
                    bf[nt] = *(const h8*)&BtL[(nt * 16 + l15) * 136 + ko];
#pragma unroll
                for (int mt = 0; mt < 2; mt++)
#pragma unroll
                    for (int nt = 0; nt < 4; nt++)
                        acc[mt][nt] = __builtin_amdgcn_mfma_f32_16x16x32_f16(a0[mt], bf[nt], acc[mt][nt], 0, 0, 0);
            }
            // half 1 (cols +4..7)
            {
                h8 a1[2];
#pragma unroll
                for (int mt = 0; mt < 2; mt++) {
#pragma unroll
                    for (int j = 0; j < 4; j++) {
                        float x1 = (float)curS[mt][4 + j], x2 = (float)curD[mt][4 + j];
                        a1[mt][2 * j]     = (_Float16)(x1 * x2);
                        a1[mt][2 * j + 1] = (_Float16)fabsf(x1 - x2);
                    }
                }
                h8 bf[4];
#pragma unroll
                for (int nt = 0; nt < 4; nt++)
                    bf[nt] = *(const h8*)&BtL[(nt * 16 + l15) * 136 + ko + 32];
#pragma unroll
                for (int mt = 0; mt < 2; mt++)
#pragma unroll
                    for (int nt = 0; nt < 4; nt++)
                        acc[mt][nt] = __builtin_amdgcn_mfma_f32_16x16x32_f16(a1[mt], bf[nt], acc[mt][nt], 0, 0, 0);
            }
            if (kk < 7) {
#pragma unroll
                for (int mt = 0; mt < 2; mt++) { curS[mt] = nxtS[mt]; curD[mt] = nxtD[mt]; }
            }
        }
    }

    // struct features step (k' = 512..543, only 512/513 nonzero)
    __syncthreads();
    {
        const int r = tid >> 2, ck = tid & 3;
        *(h8*)&BtL[r * 136 + ck * 8] = *(const h8*)(BtG + (size_t)r * 544 + 512 + ck * 8);
    }
    __syncthreads();
    {
        h8 bf[4];
#pragma unroll
        for (int nt = 0; nt < 4; nt++)
            bf[nt] = *(const h8*)&BtL[(nt * 16 + l15) * 136 + q * 8];
#pragma unroll
        for (int mt = 0; mt < 2; mt++) {
            h8 a = (h8){0, 0, 0, 0, 0, 0, 0, 0};
            if (q == 0) {
                a[0] = (_Float16)(la[mt] + lb[mt]);
                a[1] = (_Float16)fabsf(la[mt] - lb[mt]);
            }
#pragma unroll
            for (int nt = 0; nt < 4; nt++)
                acc[mt][nt] = __builtin_amdgcn_mfma_f32_16x16x32_f16(a, bf[nt], acc[mt][nt], 0, 0, 0);
        }
    }

    float b1v[4], w2v[4];
#pragma unroll
    for (int nt = 0; nt < 4; nt++) {
        int col = nt * 16 + l15;
        b1v[nt] = eb1[col];
        w2v[nt] = ew2[col];
    }
    const float b2s = eb2[0];
    float part[2][4];
#pragma unroll
    for (int mt = 0; mt < 2; mt++)
#pragma unroll
        for (int reg = 0; reg < 4; reg++) {
            float s = 0.f;
#pragma unroll
            for (int nt = 0; nt < 4; nt++) {
                float v = acc[mt][nt][reg] + b1v[nt];
                s += fmaxf(v, 0.f) * w2v[nt];
            }
            part[mt][reg] = s;
        }
#pragma unroll
    for (int off = 1; off < 16; off <<= 1)
#pragma unroll
        for (int mt = 0; mt < 2; mt++)
#pragma unroll
            for (int reg = 0; reg < 4; reg++)
                part[mt][reg] += __shfl_xor(part[mt][reg], off, 64);
    if (l15 == 0) {
#pragma unroll
        for (int mt = 0; mt < 2; mt++)
#pragma unroll
            for (int reg = 0; reg < 4; reg++) {
                int er = eb + wid * 32 + mt * 16 + q * 4 + reg;
                if (er < E2P) {
                    float xr = part[mt][reg] + b2s;
                    wsym2[er] = 0.8f / (1.0f + __expf(-xr));   // sorted index
                }
            }
    }
}

// ======== BP: locality-sorted pairs; packed state; kprod-recompute exclusion ========

// symmetric K-product: f = m @ exp(w*Rs), 36 unique exps (Rs symmetric)
__device__ __forceinline__ void kprod(const float* __restrict__ RsL, float w,
                                      const float* me, const float* mr,
                                      float* fe, float* fr) {
#pragma unroll
    for (int d = 0; d < 8; d++) { fe[d] = 0.f; fr[d] = 0.f; }
#pragma unroll
    for (int c = 0; c < 8; c++) {
        {
            float kv = __expf(w * RsL[c * 8 + c]);
            fe[c] += me[c] * kv;
            fr[c] += mr[c] * kv;
        }
#pragma unroll
        for (int d = c + 1; d < 8; d++) {
            float kv = __expf(w * RsL[c * 8 + d]);
            fe[d] += me[c] * kv; fr[d] += mr[c] * kv;
            fe[c] += me[d] * kv; fr[c] += mr[d] * kv;
        }
    }
}

// init (sorted index i): write packed state + m + logf
__global__ __launch_bounds__(256) void k_init(const int2* __restrict__ eiS,
        const float* __restrict__ wsym2, const float* __restrict__ degc,
        const float* __restrict__ Rs, const float* __restrict__ Z,
        const int* __restrict__ pos, const int* __restrict__ order,
        i4* __restrict__ prc, float2* __restrict__ wn,
        _Float16* __restrict__ M, _Float16* __restrict__ logf) {
    __shared__ float RsL[64];
    const int tid = threadIdx.x;
    if (tid < 64) RsL[tid] = Rs[tid];
    __syncthreads();
    int i = xcd_swz(blockIdx.x, EBLK) * 256 + tid;
    if (i >= E2P) return;
    int p = order[i];
    int2 sd = eiS[i];
    int sp = sd.x, dp = sd.y;
    float w = wsym2[i];
    float nrm = rsqrtf(degc[sp] * degc[dp]);
    int pz0 = pos[p], pz1 = pos[E2P + p];
    prc[i] = (i4){sp, dp, pz0, pz1};
    wn[i] = make_float2(w, nrm);
    const f4* Zs = (const f4*)(Z + (size_t)sp * 16);
    const f4* Zd = (const f4*)(Z + (size_t)dp * 16);
    f4 ls0 = Zs[0], ls1 = Zs[1], ld0 = Zd[0], ld1 = Zd[1];
    float lps[8], lpd[8];
#pragma unroll
    for (int u = 0; u < 4; u++) { lps[u] = ls0[u]; lps[4+u] = ls1[u]; lpd[u] = ld0[u]; lpd[4+u] = ld1[u]; }
    float me[8], mr[8];
    {
        float mx = lps[0], mx2 = lpd[0];
#pragma unroll
        for (int d = 1; d < 8; d++) { mx = fmaxf(mx, lps[d]); mx2 = fmaxf(mx2, lpd[d]); }
        float s = 0.f, s2 = 0.f;
#pragma unroll
        for (int d = 0; d < 8; d++) { me[d] = __expf(lps[d] - mx); s += me[d];
                                      mr[d] = __expf(lpd[d] - mx2); s2 += mr[d]; }
        float rs = 1.f / s, rs2 = 1.f / s2;
#pragma unroll
        for (int d = 0; d < 8; d++) { me[d] *= rs; mr[d] *= rs2; }
    }
    {
        h8 mh, mh2;
#pragma unroll
        for (int d = 0; d < 8; d++) { mh[d] = (_Float16)me[d]; mh2[d] = (_Float16)mr[d]; }
        *(h8*)(M + (size_t)i * 16)     = mh;
        *(h8*)(M + (size_t)i * 16 + 8) = mh2;
    }
    float fe[8], fr[8];
    kprod(RsL, w, me, mr, fe, fr);
    h8 le, lr;
#pragma unroll
    for (int d = 0; d < 8; d++) {
        le[d] = (_Float16)(__logf(fmaxf(fe[d], 1e-12f)) * nrm);
        lr[d] = (_Float16)(__logf(fmaxf(fr[d], 1e-12f)) * nrm);
    }
    *(h8*)(logf + (size_t)pz0 * 8) = le;   // -> dp's segment
    *(h8*)(logf + (size_t)pz1 * 8) = lr;   // -> sp's segment
}

// fused BP step (sorted index i): exclusion via kprod recompute (verified config)
__global__ __launch_bounds__(256) void k_bpF(const i4* __restrict__ prc,
        const float2* __restrict__ wn, const float* __restrict__ Rs,
        const float* __restrict__ Z, _Float16* __restrict__ M,
        _Float16* __restrict__ logf) {
    __shared__ float RsL[64];
    const int tid = threadIdx.x;
    if (tid < 64) RsL[tid] = Rs[tid];
    __syncthreads();
    int i = xcd_swz(blockIdx.x, EBLK) * 256 + tid;
    if (i >= E2P) return;
    i4 c4 = prc[i];
    const int sp = c4[0], dp = c4[1], pz0 = c4[2], pz1 = c4[3];
    float2 wnv = wn[i];
    const float w = wnv.x, nrm = wnv.y;
    const float alpha = Rs[64];
    h8 mhe = *(const h8*)(M + (size_t)i * 16);
    h8 mhr = *(const h8*)(M + (size_t)i * 16 + 8);
    float me[8], mr[8];
#pragma unroll
    for (int d = 0; d < 8; d++) { me[d] = (float)mhe[d]; mr[d] = (float)mhr[d]; }
    float fe[8], fr[8];
    kprod(RsL, w, me, mr, fe, fr);
    float lfe[8], lfr[8];
#pragma unroll
    for (int d = 0; d < 8; d++) {
        lfe[d] = __logf(fmaxf(fe[d], 1e-12f)) * nrm;
        lfr[d] = __logf(fmaxf(fr[d], 1e-12f)) * nrm;
    }
    const f4* Zs = (const f4*)(Z + (size_t)sp * 16);
    const f4* Zd = (const f4*)(Z + (size_t)dp * 16);
    f4 ls0 = Zs[0], ls1 = Zs[1], ss0 = Zs[2], ss1 = Zs[3];
    f4 ld0 = Zd[0], ld1 = Zd[1], sd0 = Zd[2], sd1 = Zd[3];
    float te[8], tr[8];
#pragma unroll
    for (int u = 0; u < 4; u++) {
        te[u]     = ls0[u] + alpha * (ss0[u] - lfr[u]);
        te[4 + u] = ls1[u] + alpha * (ss1[u] - lfr[4 + u]);
        tr[u]     = ld0[u] + alpha * (sd0[u] - lfe[u]);
        tr[4 + u] = ld1[u] + alpha * (sd1[u] - lfe[4 + u]);
    }
    float m1[8], m2[8];
    {
        float mx = te[0], mx2 = tr[0];
#pragma unroll
        for (int d = 1; d < 8; d++) { mx = fmaxf(mx, te[d]); mx2 = fmaxf(mx2, tr[d]); }
        float s = 0.f, s2 = 0.f;
#pragma unroll
        for (int d = 0; d < 8; d++) { m1[d] = __expf(te[d] - mx); s += m1[d];
                                      m2[d] = __expf(tr[d] - mx2); s2 += m2[d]; }
        float rs = 1.f / s, rs2 = 1.f / s2;
        float t1 = 0.f, t2 = 0.f;
#pragma unroll
        for (int d = 0; d < 8; d++) {
            m1[d] = fmaxf(0.8f * me[d] + 0.2f * m1[d] * rs, 1e-12f);  t1 += m1[d];
            m2[d] = fmaxf(0.8f * mr[d] + 0.2f * m2[d] * rs2, 1e-12f); t2 += m2[d];
        }
        float rt1 = 1.f / t1, rt2 = 1.f / t2;
#pragma unroll
        for (int d = 0; d < 8; d++) { m1[d] *= rt1; m2[d] *= rt2; }
    }
    {
        h8 mh, mh2;
#pragma unroll
        for (int d = 0; d < 8; d++) { mh[d] = (_Float16)m1[d]; mh2[d] = (_Float16)m2[d]; }
        *(h8*)(M + (size_t)i * 16)     = mh;
        *(h8*)(M + (size_t)i * 16 + 8) = mh2;
    }
    // new log_f for next iteration's sum
    float fe2[8], fr2[8];
    kprod(RsL, w, m1, m2, fe2, fr2);
    h8 le, lr;
#pragma unroll
    for (int d = 0; d < 8; d++) {
        le[d] = (_Float16)(__logf(fmaxf(fe2[d], 1e-12f)) * nrm);
        lr[d] = (_Float16)(__logf(fmaxf(fr2[d], 1e-12f)) * nrm);
    }
    *(h8*)(logf + (size_t)pz0 * 8) = le;
    *(h8*)(logf + (size_t)pz1 * 8) = lr;
}

// ---------------- sum_in: CSR reduction, h8 loads + 8-lane fold-reduce ----------------
// cnt derived from base[n+1]-base[n] (base SCN-sized; counts beyond NN are zero).
// fin==0: write S to Z[n][8+j].  fin==1: beliefs = softmax(log_phi + alpha*S) -> out.
__global__ void k_sum(const _Float16* __restrict__ logf, const int* __restrict__ base,
                      float* __restrict__ Z, const float* __restrict__ Rs,
                      float* __restrict__ out, int fin) {
    int g = blockIdx.x * 256 + threadIdx.x;
    int n = g >> 3;
    if (n >= NN) return;
    int j = threadIdx.x & 7;
    int b = base[n], cnt = base[n + 1] - b;
    float acc[8];
#pragma unroll
    for (int d = 0; d < 8; d++) acc[d] = 0.f;
    for (int s = j; s < cnt; s += 8) {
        h8 v = *(const h8*)(logf + (size_t)(b + s) * 8);
#pragma unroll
        for (int d = 0; d < 8; d++) acc[d] += (float)v[d];
    }
    int lane = threadIdx.x & 63;
    float v4[4], v2[2], r;
    {
        bool hi = (lane & 4) != 0;
#pragma unroll
        for (int i = 0; i < 4; i++) {
            float send = hi ? acc[i] : acc[i + 4];
            float recv = __shfl_xor(send, 4, 64);
            v4[i] = (hi ? acc[i + 4] : acc[i]) + recv;
        }
    }
    {
        bool hi = (lane & 2) != 0;
#pragma unroll
        for (int i = 0; i < 2; i++) {
            float send = hi ? v4[i] : v4[i + 2];
            float recv = __shfl_xor(send, 2, 64);
            v2[i] = (hi ? v4[i + 2] : v4[i]) + recv;
        }
    }
    {
        bool hi = (lane & 1) != 0;
        float send = hi ? v2[0] : v2[1];
        float recv = __shfl_xor(send, 1, 64);
        r = (hi ? v2[1] : v2[0]) + recv;
    }
    if (!fin) {
        Z[(size_t)n * 16 + 8 + j] = r;
    } else {
        float alpha = Rs[64];
        float v = Z[(size_t)n * 16 + j] + alpha * r;
        float mx = v;
        mx = fmaxf(mx, __shfl_xor(mx, 1, 64));
        mx = fmaxf(mx, __shfl_xor(mx, 2, 64));
        mx = fmaxf(mx, __shfl_xor(mx, 4, 64));
        float ex = __expf(v - mx);
        float s = ex;
        s += __shfl_xor(s, 1, 64); s += __shfl_xor(s, 2, 64); s += __shfl_xor(s, 4, 64);
        out[(size_t)n * 8 + j] = ex / s;
    }
}

extern "C" void kernel_launch(void* const* d_in, const int* in_sizes, int n_in,
                              void* d_out, int out_size, void* d_ws, size_t ws_size,
                              hipStream_t stream) {
    if (ws_size < WS_NEED) return;
    const float* x        = (const float*)d_in[0];
    const int*   ei       = (const int*)d_in[1];
    const float* enc_w1   = (const float*)d_in[3];
    const float* enc_b1   = (const float*)d_in[4];
    const float* enc_w2   = (const float*)d_in[5];
    const float* enc_b2   = (const float*)d_in[6];
    const float* edge_w1  = (const float*)d_in[7];
    const float* edge_b1  = (const float*)d_in[8];
    const float* edge_w2  = (const float*)d_in[9];
    const float* edge_b2  = (const float*)d_in[10];
    const float* R_raw    = (const float*)d_in[11];
    const float* Rsl      = (const float*)d_in[12];
    const float* mlog     = (const float*)d_in[13];

    char* ws = (char*)d_ws;
    _Float16* hf     = (_Float16*)(ws + OFF_HF16);
    _Float16* logfb  = (_Float16*)(ws + OFF_LOGF);
    float* Zb        = (float*)(ws + OFF_Z);
    int*   deg       = (int*)  (ws + OFF_DEG);    // inclA scan scratch
    float* logdeg    = (float*)(ws + OFF_LOGDEG);
    float* degc      = (float*)(ws + OFF_DEGC);
    int*   baseA     = (int*)  (ws + OFF_BASE);
    int*   cnt       = (int*)  (ws + OFF_CNT);    // dst counters -> deg counts
    int*   blk       = (int*)  (ws + OFF_BLK);
    _Float16* Wt     = (_Float16*)(ws + OFF_WT);
    _Float16* Bt     = (_Float16*)(ws + OFF_BT);
    float* Rs        = (float*)(ws + OFF_RS);
    float* wsym2     = (float*)(ws + OFF_WSYM);
    int*   pos       = (int*)  (ws + OFF_POS);    // ranks, then final slots
    int*   order     = (int*)  (ws + OFF_ORDER);
    int*   base2     = (int*)  (ws + OFF_BASE2);
    int*   ofs2      = (int*)  (ws + OFF_OFS2);   // key counters -> key counts
    i4*    prc       = (i4*)   (ws + OFF_PRC);    // head doubles as inclB scratch
    float2* wnb      = (float2*)(ws + OFF_WN);
    _Float16* Mb     = (_Float16*)(ws + OFF_M);
    int2*  eiS       = (int2*) (ws + OFF_EIS);
    int*   rk2       = (int*)  (ws + OFF_RK2);
    float* outp      = (float*)d_out;

    hipMemsetAsync(cnt, 0, (size_t)SCN * 4, stream);
    hipMemsetAsync(ofs2, 0, (size_t)SCN * 4, stream);
    k_rank<<<dim3(EDD / 256), dim3(256), 0, stream>>>(ei, cnt, ofs2, pos, rk2);
    k_prep<<<dim3((256 * 512 + 64 * 544 + 65 + 255) / 256), dim3(256), 0, stream>>>(
        enc_w1, edge_w1, R_raw, Rsl, mlog, Wt, Bt, Rs);
    // dual CSR bases (one-time): dst-CSR + pair-locality-key CSR in one scan pipeline
    k_scanA<<<dim3(NBLK), dim3(256), 0, stream>>>(cnt, ofs2, deg /*inclA*/,
                                                  (int*)prc /*inclB*/, blk, logdeg, degc);
    k_scanB<<<dim3(1), dim3(256), 0, stream>>>(blk);
    k_scanC<<<dim3(NBLK), dim3(256), 0, stream>>>(deg, cnt, (int*)prc, ofs2, blk,
                                                  baseA, base2);
    k_fill<<<dim3(EDD / 256), dim3(256), 0, stream>>>(ei, baseA, base2, rk2,
                                                      pos, order, eiS);
    // encoder + edge MLP
    k_enc<<<dim3((NN + 63) / 64), dim3(256), 0, stream>>>(x, Wt, enc_b1, hf);
    k_logits<<<dim3(NBLK), dim3(256), 0, stream>>>(hf, enc_w2, enc_b2, Zb);
    k_edge<<<dim3(E2P / 128), dim3(256), 0, stream>>>(eiS, hf, logdeg, Bt, edge_b1,
                                                      edge_w2, edge_b2, wsym2);
    // BP loop (logfb aliases hf — hf is dead from here on)
    k_init<<<dim3(EBLK), dim3(256), 0, stream>>>(eiS, wsym2, degc, Rs, Zb, pos, order,
                                                 prc, wnb, Mb, logfb);
    k_sum<<<dim3((NN * 8 + 255) / 256), dim3(256), 0, stream>>>(logfb, baseA, Zb,
                                                                Rs, outp, 0);
    for (int t = 0; t < 10; t++) {
        k_bpF<<<dim3(EBLK), dim3(256), 0, stream>>>(prc, wnb, Rs, Zb, Mb, logfb);
        k_sum<<<dim3((NN * 8 + 255) / 256), dim3(256), 0, stream>>>(logfb, baseA, Zb,
                                                                    Rs, outp, (t == 9) ? 1 : 0);
    }
    (void)in_sizes; (void)n_in; (void)out_size;
}